// Round 3
// baseline (639.535 us; speedup 1.0000x reference)
//
#include <hip/hip_runtime.h>
#include <cstdint>
#include <cstddef>

// Problem constants (fixed by the reference).
#define NUM_AUDIOS 64
#define NODES_PER  800
#define NN         51200
#define EE         409600
// IN_C=512, HID=256, OUT=256, HEADS=2 -> both GAT linears output [N, 512] (2 heads x 256)

typedef __attribute__((ext_vector_type(8))) unsigned short ushort8;
typedef __attribute__((ext_vector_type(4))) unsigned short ushort4v;
typedef __attribute__((ext_vector_type(8))) __bf16 bf16x8;
typedef __attribute__((ext_vector_type(4))) float f32x4;

__device__ __forceinline__ float b2f(unsigned short h) {
  return __uint_as_float(((unsigned)h) << 16);
}
__device__ __forceinline__ unsigned short f2b(float f) {
  unsigned u = __float_as_uint(f);
  u += 0x7fffu + ((u >> 16) & 1u);  // RNE
  return (unsigned short)(u >> 16);
}
__device__ __forceinline__ float lrelu(float v) { return v > 0.f ? v : 0.2f * v; }

// Canonical bf16 parameter block offsets (u16 units)
#define P_AS1 0
#define P_AD1 512
#define P_B1  1024
#define P_AS2 1536
#define P_AD2 2048
#define P_B2  2560
#define P_WATT 3072
#define P_BATT 3328
#define P_WCLS 3336
#define P_BCLS 3848

// ---------------- dtype probe: fp32 data read as bf16 shows huge/NaN values ----
__global__ __launch_bounds__(256) void detect_k(const unsigned short* __restrict__ x,
                                                int* __restrict__ flag) {
  __shared__ int s;
  if (threadIdx.x == 0) s = 0;
  __syncthreads();
  int big = 0;
  for (int i = threadIdx.x; i < 4096; i += 256) {
    const float v = b2f(x[i]);
    if (!(__builtin_fabsf(v) <= 1e4f)) big = 1;  // catches >1e4, inf, NaN
  }
  if (big) atomicOr(&s, 1);
  __syncthreads();
  if (threadIdx.x == 0) *flag = s;  // 1 = fp32 inputs, 0 = bf16 inputs
}

// ---------------- canonicalize x to bf16 ----------------
__global__ __launch_bounds__(256) void conv_x_k(const void* __restrict__ xraw,
                                                unsigned short* __restrict__ x16,
                                                const int* __restrict__ flag) {
  const size_t i = ((size_t)blockIdx.x * 256 + threadIdx.x) * 4;
  if (*flag) {
    const float4 v = *(const float4*)((const float*)xraw + i);
    ushort4v o;
    o[0] = f2b(v.x); o[1] = f2b(v.y); o[2] = f2b(v.z); o[3] = f2b(v.w);
    *(ushort4v*)(x16 + i) = o;
  } else {
    *(ushort4v*)(x16 + i) = *(const ushort4v*)((const unsigned short*)xraw + i);
  }
}

// ---------------- canonicalize the small parameter tensors ----------------
__global__ __launch_bounds__(256) void conv_params_k(
    const void* p0, const void* p1, const void* p2, const void* p3, const void* p4,
    const void* p5, const void* p6, const void* p7, const void* p8, const void* p9,
    unsigned short* __restrict__ dst, const int* __restrict__ flag) {
  const void* srcs[10] = {p0, p1, p2, p3, p4, p5, p6, p7, p8, p9};
  const int offs[10] = {P_AS1, P_AD1, P_B1, P_AS2, P_AD2, P_B2, P_WATT, P_BATT, P_WCLS, P_BCLS};
  const int lens[10] = {512, 512, 256, 512, 512, 256, 256, 1, 512, 2};
  const int b = blockIdx.x;
  const int f = *flag;
  for (int i = threadIdx.x; i < lens[b]; i += 256) {
    dst[offs[b] + i] = f ? f2b(((const float*)srcs[b])[i])
                         : ((const unsigned short*)srcs[b])[i];
  }
}

// ---------------- fused convert + transpose: W [K, Nc] -> WT [Nc, K] bf16 -------
__global__ __launch_bounds__(256) void transpose_k(const void* __restrict__ W,
                                                   unsigned short* __restrict__ WT,
                                                   const int* __restrict__ flag,
                                                   int K, int Nc) {
  const int idx = blockIdx.x * 256 + threadIdx.x;  // grid sized exactly K*Nc/256
  const int n = idx / K, k = idx - n * K;
  WT[idx] = (*flag) ? f2b(((const float*)W)[(size_t)k * Nc + n])
                    : ((const unsigned short*)W)[(size_t)k * Nc + n];
}

// ---------------- GEMM: C[M,Nn] = A[M,K] @ B, with B given transposed BT[Nn,K] ----
// 128x128 tile, BK=32, 256 threads (4 waves as 2x2 of 64x64), mfma 16x16x32 bf16.
__global__ __launch_bounds__(256) void gemm_bt(const unsigned short* __restrict__ A,
                                               const unsigned short* __restrict__ BT,
                                               unsigned short* __restrict__ C,
                                               int K, int Nn) {
  __shared__ unsigned short As[128 * 32];
  __shared__ unsigned short Bs[128 * 32];
  const int tid = threadIdx.x;
  const int wave = tid >> 6, lane = tid & 63;
  const int m0 = blockIdx.y * 128, n0 = blockIdx.x * 128;
  const int wm = wave >> 1, wn = wave & 1;
  const int row = lane & 15, quad = lane >> 4;
  f32x4 acc[4][4];
#pragma unroll
  for (int i = 0; i < 4; ++i)
#pragma unroll
    for (int j = 0; j < 4; ++j) acc[i][j] = (f32x4){0.f, 0.f, 0.f, 0.f};

  for (int k0 = 0; k0 < K; k0 += 32) {
    ushort8 av[2], bv[2];
#pragma unroll
    for (int r = 0; r < 2; ++r) {
      const int cc = r * 256 + tid;
      const int arow = cc >> 2, kc = (cc & 3) * 8;
      av[r] = *(const ushort8*)&A[(size_t)(m0 + arow) * K + k0 + kc];
      bv[r] = *(const ushort8*)&BT[(size_t)(n0 + arow) * K + k0 + kc];
    }
    __syncthreads();  // protect previous iteration's LDS readers
#pragma unroll
    for (int r = 0; r < 2; ++r) {
      const int cc = r * 256 + tid;
      *(ushort8*)&As[(size_t)cc * 8] = av[r];
      *(ushort8*)&Bs[(size_t)cc * 8] = bv[r];
    }
    __syncthreads();

    bf16x8 af[4], bq[4];
#pragma unroll
    for (int i = 0; i < 4; ++i) {
      af[i] = *(const bf16x8*)&As[(wm * 64 + i * 16 + row) * 32 + quad * 8];
      bq[i] = *(const bf16x8*)&Bs[(wn * 64 + i * 16 + row) * 32 + quad * 8];
    }
#pragma unroll
    for (int i = 0; i < 4; ++i)
#pragma unroll
      for (int j = 0; j < 4; ++j)
        acc[i][j] = __builtin_amdgcn_mfma_f32_16x16x32_bf16(af[i], bq[j], acc[i][j], 0, 0, 0);
  }

  // C/D layout (verified m89/m91): col = lane&15, row = quad*4 + reg
  const int col = lane & 15;
#pragma unroll
  for (int i = 0; i < 4; ++i)
#pragma unroll
    for (int j = 0; j < 4; ++j)
#pragma unroll
      for (int r = 0; r < 4; ++r) {
        const int gm = m0 + wm * 64 + i * 16 + quad * 4 + r;
        const int gn = n0 + wn * 64 + j * 16 + col;
        C[(size_t)gm * Nn + gn] = f2b(acc[i][j][r]);
      }
}

// ---------------- per-node attention logits: al_s/al_d [N,2] fp32 ----------------
__global__ __launch_bounds__(256) void al_k(const unsigned short* __restrict__ h,
                                            const unsigned short* __restrict__ a_s,
                                            const unsigned short* __restrict__ a_d,
                                            float* __restrict__ al_s, float* __restrict__ al_d) {
  const int wave = threadIdx.x >> 6, lane = threadIdx.x & 63;
  const int n = blockIdx.x * 4 + wave;
  const ushort8 hv = *(const ushort8*)&h[(size_t)n * 512 + lane * 8];
  const ushort8 sv = *(const ushort8*)&a_s[lane * 8];
  const ushort8 dv = *(const ushort8*)&a_d[lane * 8];
  float ps = 0.f, pd = 0.f;
#pragma unroll
  for (int j = 0; j < 8; ++j) {
    const float hf = b2f(hv[j]);
    ps += hf * b2f(sv[j]);
    pd += hf * b2f(dv[j]);
  }
#pragma unroll
  for (int off = 1; off < 32; off <<= 1) {  // reduce within 32-lane half (one head)
    ps += __shfl_xor(ps, off);
    pd += __shfl_xor(pd, off);
  }
  if ((lane & 31) == 0) {
    const int head = lane >> 5;
    al_s[n * 2 + head] = ps;
    al_d[n * 2 + head] = pd;
  }
}

// ---------------- CSR build ----------------
__global__ __launch_bounds__(256) void hist_k(const int* __restrict__ dst, int* __restrict__ counts) {
  const int e = blockIdx.x * 256 + threadIdx.x;
  atomicAdd(&counts[dst[e]], 1);
}

__global__ __launch_bounds__(256) void rowptr_k(const int* __restrict__ counts, int* __restrict__ row_ptr) {
  __shared__ int sh[800];
  __shared__ int pre[200];
  const int a = blockIdx.x, t = threadIdx.x;
  for (int i = t; i < 800; i += 256) sh[i] = counts[a * 800 + i];
  __syncthreads();
  if (t < 200) pre[t] = sh[t * 4] + sh[t * 4 + 1] + sh[t * 4 + 2] + sh[t * 4 + 3];
  __syncthreads();
  if (t == 0) {
    int run = 0;
    for (int i = 0; i < 200; ++i) { const int v = pre[i]; pre[i] = run; run += v; }
  }
  __syncthreads();
  if (t < 200) {
    int b = a * 6400 + pre[t];
#pragma unroll
    for (int j = 0; j < 4; ++j) { row_ptr[a * 800 + t * 4 + j] = b; b += sh[t * 4 + j]; }
  }
}

__global__ __launch_bounds__(256) void scatter_k(const int* __restrict__ src, const int* __restrict__ dst,
                                                 const int* __restrict__ row_ptr, int* __restrict__ cursor,
                                                 int* __restrict__ ssrc) {
  const int e = blockIdx.x * 256 + threadIdx.x;
  const int d = dst[e];
  const int p = atomicAdd(&cursor[d], 1);
  ssrc[row_ptr[d] + p] = src[e];
}

// ---------------- GAT aggregate: one wave per node ----------------
__global__ __launch_bounds__(256) void agg_k(const unsigned short* __restrict__ h,
                                             const float* __restrict__ al_s, const float* __restrict__ al_d,
                                             const int* __restrict__ row_ptr, const int* __restrict__ counts,
                                             const int* __restrict__ ssrc, const unsigned short* __restrict__ bias,
                                             unsigned short* __restrict__ out, int do_relu) {
  const int wave = threadIdx.x >> 6, lane = threadIdx.x & 63;
  const int n = blockIdx.x * 4 + wave;
  const int head = lane >> 5;  // lanes 0-31: head0 cols, 32-63: head1 cols
  const int deg = counts[n];
  const int base = row_ptr[n];
  const float ald = al_d[n * 2 + head];
  const float self_e = lrelu(al_s[n * 2 + head] + ald);
  float mx = self_e;
  for (int i = 0; i < deg; ++i) {
    const int s = ssrc[base + i];
    mx = fmaxf(mx, lrelu(al_s[s * 2 + head] + ald));
  }
  float acc[8];
  float den;
  {
    const float w = __expf(self_e - mx);
    den = w;
    const ushort8 hv = *(const ushort8*)&h[(size_t)n * 512 + lane * 8];
#pragma unroll
    for (int j = 0; j < 8; ++j) acc[j] = w * b2f(hv[j]);
  }
  for (int i = 0; i < deg; ++i) {
    const int s = ssrc[base + i];
    const float w = __expf(lrelu(al_s[s * 2 + head] + ald) - mx);
    den += w;
    const ushort8 hv = *(const ushort8*)&h[(size_t)s * 512 + lane * 8];
#pragma unroll
    for (int j = 0; j < 8; ++j) acc[j] += w * b2f(hv[j]);
  }
  const float inv = 1.f / den;
  const int c0 = (lane & 31) * 8;
  ushort8 res;
#pragma unroll
  for (int j = 0; j < 8; ++j) {
    const float mine = acc[j] * inv;
    const float other = __shfl_xor(mine, 32);  // partner lane holds other head, same cols
    float o = (mine + other) * 0.5f + b2f(bias[c0 + j]);
    if (do_relu) o = fmaxf(o, 0.f);
    res[j] = f2b(o);
  }
  if (lane < 32) *(ushort8*)&out[(size_t)n * 256 + c0] = res;
}

// ---------------- per-audio temporal attention + classifier (fp32 out) ----------
__global__ __launch_bounds__(256) void temporal_k(const unsigned short* __restrict__ emb,
                                                  const unsigned short* __restrict__ w_att,
                                                  const unsigned short* __restrict__ b_att,
                                                  const unsigned short* __restrict__ w_cls,
                                                  const unsigned short* __restrict__ b_cls,
                                                  float* __restrict__ out_audio) {
  const int a = blockIdx.x;
  const int t = threadIdx.x, wave = t >> 6, lane = t & 63;
  __shared__ float lg[800];
  __shared__ float red[256];
  float wv[4];
  {
    const ushort4v w4 = *(const ushort4v*)&w_att[lane * 4];
#pragma unroll
    for (int j = 0; j < 4; ++j) wv[j] = b2f(w4[j]);
  }
  const size_t nb = (size_t)a * 800;
  const float batt = b2f(b_att[0]);
  for (int i = wave; i < 800; i += 4) {
    const ushort4v e4 = *(const ushort4v*)&emb[(nb + i) * 256 + lane * 4];
    float d = 0.f;
#pragma unroll
    for (int j = 0; j < 4; ++j) d += b2f(e4[j]) * wv[j];
#pragma unroll
    for (int off = 32; off >= 1; off >>= 1) d += __shfl_xor(d, off);
    if (lane == 0) lg[i] = d + batt;
  }
  __syncthreads();
  float m = -1e30f;
  for (int i = t; i < 800; i += 256) m = fmaxf(m, lg[i]);
  red[t] = m; __syncthreads();
  for (int s = 128; s >= 1; s >>= 1) { if (t < s) red[t] = fmaxf(red[t], red[t + s]); __syncthreads(); }
  const float mx = red[0];
  __syncthreads();
  float sum = 0.f;
  for (int i = t; i < 800; i += 256) { const float w = __expf(lg[i] - mx); lg[i] = w; sum += w; }
  red[t] = sum; __syncthreads();
  for (int s = 128; s >= 1; s >>= 1) { if (t < s) red[t] += red[t + s]; __syncthreads(); }
  const float inv = 1.f / red[0];
  __syncthreads();
  float acc = 0.f;
  for (int i = 0; i < 800; ++i) acc += lg[i] * b2f(emb[(nb + i) * 256 + t]);
  acc *= inv;
  float p0 = acc * b2f(w_cls[t * 2]);
  float p1 = acc * b2f(w_cls[t * 2 + 1]);
  red[t] = p0; __syncthreads();
  for (int s = 128; s >= 1; s >>= 1) { if (t < s) red[t] += red[t + s]; __syncthreads(); }
  const float r0 = red[0];
  __syncthreads();
  red[t] = p1; __syncthreads();
  for (int s = 128; s >= 1; s >>= 1) { if (t < s) red[t] += red[t + s]; __syncthreads(); }
  const float r1 = red[0];
  if (t == 0) {
    out_audio[a * 2]     = r0 + b2f(b_cls[0]);
    out_audio[a * 2 + 1] = r1 + b2f(b_cls[1]);
  }
}

// ---------------- emit d_out in the detected dtype ----------------
__global__ __launch_bounds__(256) void emit_k(const unsigned short* __restrict__ emb16,
                                              const float* __restrict__ audio,
                                              void* __restrict__ out, const int* __restrict__ flag) {
  const int i = blockIdx.x * 256 + threadIdx.x;
  const int total = NN * 256 + NUM_AUDIOS * 2;
  if (i >= total) return;
  float v; unsigned short u;
  if (i < NN * 256) { u = emb16[i]; v = b2f(u); }
  else { v = audio[i - NN * 256]; u = f2b(v); }
  if (*flag) ((float*)out)[i] = v;
  else       ((unsigned short*)out)[i] = u;
}

extern "C" void kernel_launch(void* const* d_in, const int* in_sizes, int n_in,
                              void* d_out, int out_size, void* d_ws, size_t ws_size,
                              hipStream_t stream) {
  (void)in_sizes; (void)n_in; (void)out_size; (void)ws_size;
  const void* x_raw  = d_in[0];
  const int*  eidx   = (const int*)d_in[1];
  // d_in[2] = batch (unused: audio = n / 800)
  const int* src = eidx;
  const int* dst = eidx + EE;

  char* ws = (char*)d_ws;
  size_t off = 0;
  auto alloc = [&](size_t bytes) -> void* {
    void* p = ws + off;
    off += (bytes + 255) & ~(size_t)255;
    return p;
  };
  int* flag              = (int*)alloc(256);
  unsigned short* params = (unsigned short*)alloc(4096 * 2);
  unsigned short* W1T    = (unsigned short*)alloc((size_t)512 * 512 * 2);
  unsigned short* W2T    = (unsigned short*)alloc((size_t)512 * 256 * 2);
  unsigned short* x16    = (unsigned short*)alloc((size_t)NN * 512 * 2);  // also hosts hrel + emb16
  unsigned short* hbig   = (unsigned short*)alloc((size_t)NN * 512 * 2);
  float* al_s   = (float*)alloc((size_t)NN * 2 * 4);
  float* al_d   = (float*)alloc((size_t)NN * 2 * 4);
  int*   counts = (int*)alloc((size_t)NN * 4);
  int*   rowp   = (int*)alloc((size_t)NN * 4);
  int*   cursor = (int*)alloc((size_t)NN * 4);
  int*   ssrc   = (int*)alloc((size_t)EE * 4);
  float* audio  = (float*)alloc(NUM_AUDIOS * 2 * 4);
  // Aliases into x16's region (x16 is dead after gemm1):
  unsigned short* hrel  = x16;                         // layer-1 relu output [NN,256]
  unsigned short* emb16 = x16 + (size_t)NN * 256;      // node_emb [NN,256]

  detect_k<<<dim3(1), 256, 0, stream>>>((const unsigned short*)x_raw, flag);

  hipMemsetAsync(counts, 0, (size_t)NN * 4, stream);
  hipMemsetAsync(cursor, 0, (size_t)NN * 4, stream);

  conv_x_k<<<dim3(NN * 512 / 4 / 256), 256, 0, stream>>>(x_raw, x16, flag);
  conv_params_k<<<dim3(10), 256, 0, stream>>>(d_in[4], d_in[5], d_in[6], d_in[8], d_in[9],
                                              d_in[10], d_in[11], d_in[12], d_in[13], d_in[14],
                                              params, flag);
  transpose_k<<<dim3(512 * 512 / 256), 256, 0, stream>>>(d_in[3], W1T, flag, 512, 512);
  transpose_k<<<dim3(512 * 256 / 256), 256, 0, stream>>>(d_in[7], W2T, flag, 256, 512);

  hist_k<<<dim3(EE / 256), 256, 0, stream>>>(dst, counts);
  rowptr_k<<<dim3(NUM_AUDIOS), 256, 0, stream>>>(counts, rowp);
  scatter_k<<<dim3(EE / 256), 256, 0, stream>>>(src, dst, rowp, cursor, ssrc);

  // Layer 1
  gemm_bt<<<dim3(4, 400), 256, 0, stream>>>(x16, W1T, hbig, 512, 512);
  al_k<<<dim3(NN / 4), 256, 0, stream>>>(hbig, params + P_AS1, params + P_AD1, al_s, al_d);
  agg_k<<<dim3(NN / 4), 256, 0, stream>>>(hbig, al_s, al_d, rowp, counts, ssrc,
                                          params + P_B1, hrel, 1);

  // Layer 2
  gemm_bt<<<dim3(4, 400), 256, 0, stream>>>(hrel, W2T, hbig, 256, 512);
  al_k<<<dim3(NN / 4), 256, 0, stream>>>(hbig, params + P_AS2, params + P_AD2, al_s, al_d);
  agg_k<<<dim3(NN / 4), 256, 0, stream>>>(hbig, al_s, al_d, rowp, counts, ssrc,
                                          params + P_B2, emb16, 0);

  // Temporal attention + classifier
  temporal_k<<<dim3(NUM_AUDIOS), 256, 0, stream>>>(emb16, params + P_WATT, params + P_BATT,
                                                   params + P_WCLS, params + P_BCLS, audio);

  emit_k<<<dim3((NN * 256 + NUM_AUDIOS * 2 + 255) / 256), 256, 0, stream>>>(emb16, audio, d_out, flag);
}

// Round 4
// 532.909 us; speedup vs baseline: 1.2001x; 1.2001x over previous
//
#include <hip/hip_runtime.h>
#include <cstdint>
#include <cstddef>

// Problem constants (fixed by the reference).
#define NUM_AUDIOS 64
#define NODES_PER  800
#define NN         51200
#define EE         409600
// IN_C=512, HID=256, OUT=256, HEADS=2 -> both GAT linears output [N, 512] (2 heads x 256)

typedef __attribute__((ext_vector_type(8))) unsigned short ushort8;
typedef __attribute__((ext_vector_type(4))) unsigned short ushort4v;
typedef __attribute__((ext_vector_type(8))) __bf16 bf16x8;
typedef __attribute__((ext_vector_type(4))) float f32x4;

__device__ __forceinline__ float b2f(unsigned short h) {
  return __uint_as_float(((unsigned)h) << 16);
}
__device__ __forceinline__ unsigned short f2b(float f) {
  unsigned u = __float_as_uint(f);
  u += 0x7fffu + ((u >> 16) & 1u);  // RNE
  return (unsigned short)(u >> 16);
}
__device__ __forceinline__ float lrelu(float v) { return v > 0.f ? v : 0.2f * v; }

// Canonical bf16 parameter block offsets (u16 units)
#define P_AS1 0
#define P_AD1 512
#define P_B1  1024
#define P_AS2 1536
#define P_AD2 2048
#define P_B2  2560
#define P_WATT 3072
#define P_BATT 3328
#define P_WCLS 3336
#define P_BCLS 3848

// ---------------- dtype probe: fp32 data read as bf16 shows huge/NaN values ----
__global__ __launch_bounds__(256) void detect_k(const unsigned short* __restrict__ x,
                                                int* __restrict__ flag) {
  __shared__ int s;
  if (threadIdx.x == 0) s = 0;
  __syncthreads();
  int big = 0;
  for (int i = threadIdx.x; i < 4096; i += 256) {
    const float v = b2f(x[i]);
    if (!(__builtin_fabsf(v) <= 1e4f)) big = 1;  // catches >1e4, inf, NaN
  }
  if (big) atomicOr(&s, 1);
  __syncthreads();
  if (threadIdx.x == 0) *flag = s;  // 1 = fp32 inputs, 0 = bf16 inputs
}

// ---------------- canonicalize x to bf16 ----------------
__global__ __launch_bounds__(256) void conv_x_k(const void* __restrict__ xraw,
                                                unsigned short* __restrict__ x16,
                                                const int* __restrict__ flag) {
  const size_t i = ((size_t)blockIdx.x * 256 + threadIdx.x) * 4;
  if (*flag) {
    const float4 v = *(const float4*)((const float*)xraw + i);
    ushort4v o;
    o[0] = f2b(v.x); o[1] = f2b(v.y); o[2] = f2b(v.z); o[3] = f2b(v.w);
    *(ushort4v*)(x16 + i) = o;
  } else {
    *(ushort4v*)(x16 + i) = *(const ushort4v*)((const unsigned short*)xraw + i);
  }
}

// ---------------- canonicalize the small parameter tensors ----------------
__global__ __launch_bounds__(256) void conv_params_k(
    const void* p0, const void* p1, const void* p2, const void* p3, const void* p4,
    const void* p5, const void* p6, const void* p7, const void* p8, const void* p9,
    unsigned short* __restrict__ dst, const int* __restrict__ flag) {
  const void* srcs[10] = {p0, p1, p2, p3, p4, p5, p6, p7, p8, p9};
  const int offs[10] = {P_AS1, P_AD1, P_B1, P_AS2, P_AD2, P_B2, P_WATT, P_BATT, P_WCLS, P_BCLS};
  const int lens[10] = {512, 512, 256, 512, 512, 256, 256, 1, 512, 2};
  const int b = blockIdx.x;
  const int f = *flag;
  for (int i = threadIdx.x; i < lens[b]; i += 256) {
    dst[offs[b] + i] = f ? f2b(((const float*)srcs[b])[i])
                         : ((const unsigned short*)srcs[b])[i];
  }
}

// ---------------- fused convert + transpose: W [K, Nc] -> WT [Nc, K] bf16 -------
__global__ __launch_bounds__(256) void transpose_k(const void* __restrict__ W,
                                                   unsigned short* __restrict__ WT,
                                                   const int* __restrict__ flag,
                                                   int K, int Nc) {
  const int idx = blockIdx.x * 256 + threadIdx.x;  // grid sized exactly K*Nc/256
  const int n = idx / K, k = idx - n * K;
  WT[idx] = (*flag) ? f2b(((const float*)W)[(size_t)k * Nc + n])
                    : ((const unsigned short*)W)[(size_t)k * Nc + n];
}

// ---------------- GEMM: C[M,Nn] = A[M,K] @ B, with B given transposed BT[Nn,K] ----
// 128x128 tile, BK=32, 256 threads (4 waves as 2x2 of 64x64), mfma 16x16x32 bf16.
__global__ __launch_bounds__(256) void gemm_bt(const unsigned short* __restrict__ A,
                                               const unsigned short* __restrict__ BT,
                                               unsigned short* __restrict__ C,
                                               int K, int Nn) {
  __shared__ unsigned short As[128 * 32];
  __shared__ unsigned short Bs[128 * 32];
  const int tid = threadIdx.x;
  const int wave = tid >> 6, lane = tid & 63;
  const int m0 = blockIdx.y * 128, n0 = blockIdx.x * 128;
  const int wm = wave >> 1, wn = wave & 1;
  const int row = lane & 15, quad = lane >> 4;
  f32x4 acc[4][4];
#pragma unroll
  for (int i = 0; i < 4; ++i)
#pragma unroll
    for (int j = 0; j < 4; ++j) acc[i][j] = (f32x4){0.f, 0.f, 0.f, 0.f};

  for (int k0 = 0; k0 < K; k0 += 32) {
    ushort8 av[2], bv[2];
#pragma unroll
    for (int r = 0; r < 2; ++r) {
      const int cc = r * 256 + tid;
      const int arow = cc >> 2, kc = (cc & 3) * 8;
      av[r] = *(const ushort8*)&A[(size_t)(m0 + arow) * K + k0 + kc];
      bv[r] = *(const ushort8*)&BT[(size_t)(n0 + arow) * K + k0 + kc];
    }
    __syncthreads();  // protect previous iteration's LDS readers
#pragma unroll
    for (int r = 0; r < 2; ++r) {
      const int cc = r * 256 + tid;
      *(ushort8*)&As[(size_t)cc * 8] = av[r];
      *(ushort8*)&Bs[(size_t)cc * 8] = bv[r];
    }
    __syncthreads();

    bf16x8 af[4], bq[4];
#pragma unroll
    for (int i = 0; i < 4; ++i) {
      af[i] = *(const bf16x8*)&As[(wm * 64 + i * 16 + row) * 32 + quad * 8];
      bq[i] = *(const bf16x8*)&Bs[(wn * 64 + i * 16 + row) * 32 + quad * 8];
    }
#pragma unroll
    for (int i = 0; i < 4; ++i)
#pragma unroll
      for (int j = 0; j < 4; ++j)
        acc[i][j] = __builtin_amdgcn_mfma_f32_16x16x32_bf16(af[i], bq[j], acc[i][j], 0, 0, 0);
  }

  // C/D layout (verified m89/m91): col = lane&15, row = quad*4 + reg
  const int col = lane & 15;
#pragma unroll
  for (int i = 0; i < 4; ++i)
#pragma unroll
    for (int j = 0; j < 4; ++j)
#pragma unroll
      for (int r = 0; r < 4; ++r) {
        const int gm = m0 + wm * 64 + i * 16 + quad * 4 + r;
        const int gn = n0 + wn * 64 + j * 16 + col;
        C[(size_t)gm * Nn + gn] = f2b(acc[i][j][r]);
      }
}

// ---------------- per-node attention logits: al_s/al_d [N,2] fp32 ----------------
__global__ __launch_bounds__(256) void al_k(const unsigned short* __restrict__ h,
                                            const unsigned short* __restrict__ a_s,
                                            const unsigned short* __restrict__ a_d,
                                            float* __restrict__ al_s, float* __restrict__ al_d) {
  const int wave = threadIdx.x >> 6, lane = threadIdx.x & 63;
  const int n = blockIdx.x * 4 + wave;
  const ushort8 hv = *(const ushort8*)&h[(size_t)n * 512 + lane * 8];
  const ushort8 sv = *(const ushort8*)&a_s[lane * 8];
  const ushort8 dv = *(const ushort8*)&a_d[lane * 8];
  float ps = 0.f, pd = 0.f;
#pragma unroll
  for (int j = 0; j < 8; ++j) {
    const float hf = b2f(hv[j]);
    ps += hf * b2f(sv[j]);
    pd += hf * b2f(dv[j]);
  }
#pragma unroll
  for (int off = 1; off < 32; off <<= 1) {  // reduce within 32-lane half (one head)
    ps += __shfl_xor(ps, off);
    pd += __shfl_xor(pd, off);
  }
  if ((lane & 31) == 0) {
    const int head = lane >> 5;
    al_s[n * 2 + head] = ps;
    al_d[n * 2 + head] = pd;
  }
}

// ---------------- CSR build ----------------
__global__ __launch_bounds__(256) void hist_k(const int* __restrict__ dst, int* __restrict__ counts) {
  const int e = blockIdx.x * 256 + threadIdx.x;
  atomicAdd(&counts[dst[e]], 1);
}

__global__ __launch_bounds__(256) void rowptr_k(const int* __restrict__ counts, int* __restrict__ row_ptr) {
  __shared__ int sh[800];
  __shared__ int pre[200];
  const int a = blockIdx.x, t = threadIdx.x;
  for (int i = t; i < 800; i += 256) sh[i] = counts[a * 800 + i];
  __syncthreads();
  if (t < 200) pre[t] = sh[t * 4] + sh[t * 4 + 1] + sh[t * 4 + 2] + sh[t * 4 + 3];
  __syncthreads();
  if (t == 0) {
    int run = 0;
    for (int i = 0; i < 200; ++i) { const int v = pre[i]; pre[i] = run; run += v; }
  }
  __syncthreads();
  if (t < 200) {
    int b = a * 6400 + pre[t];
#pragma unroll
    for (int j = 0; j < 4; ++j) { row_ptr[a * 800 + t * 4 + j] = b; b += sh[t * 4 + j]; }
  }
}

__global__ __launch_bounds__(256) void scatter_k(const int* __restrict__ src, const int* __restrict__ dst,
                                                 const int* __restrict__ row_ptr, int* __restrict__ cursor,
                                                 int* __restrict__ ssrc) {
  const int e = blockIdx.x * 256 + threadIdx.x;
  const int d = dst[e];
  const int p = atomicAdd(&cursor[d], 1);
  ssrc[row_ptr[d] + p] = src[e];
}

// ---------------- GAT aggregate: one wave per node ----------------
// Optional out2: final-layer dual write of d_out in detected dtype.
__global__ __launch_bounds__(256) void agg_k(const unsigned short* __restrict__ h,
                                             const float* __restrict__ al_s, const float* __restrict__ al_d,
                                             const int* __restrict__ row_ptr, const int* __restrict__ counts,
                                             const int* __restrict__ ssrc, const unsigned short* __restrict__ bias,
                                             unsigned short* __restrict__ out, int do_relu,
                                             void* __restrict__ out2, const int* __restrict__ flagp) {
  const int wave = threadIdx.x >> 6, lane = threadIdx.x & 63;
  const int n = blockIdx.x * 4 + wave;
  const int head = lane >> 5;  // lanes 0-31: head0 cols, 32-63: head1 cols
  const int deg = counts[n];
  const int base = row_ptr[n];
  const float ald = al_d[n * 2 + head];
  const float self_e = lrelu(al_s[n * 2 + head] + ald);
  float mx = self_e;
  for (int i = 0; i < deg; ++i) {
    const int s = ssrc[base + i];
    mx = fmaxf(mx, lrelu(al_s[s * 2 + head] + ald));
  }
  float acc[8];
  float den;
  {
    const float w = __expf(self_e - mx);
    den = w;
    const ushort8 hv = *(const ushort8*)&h[(size_t)n * 512 + lane * 8];
#pragma unroll
    for (int j = 0; j < 8; ++j) acc[j] = w * b2f(hv[j]);
  }
  for (int i = 0; i < deg; ++i) {
    const int s = ssrc[base + i];
    const float w = __expf(lrelu(al_s[s * 2 + head] + ald) - mx);
    den += w;
    const ushort8 hv = *(const ushort8*)&h[(size_t)s * 512 + lane * 8];
#pragma unroll
    for (int j = 0; j < 8; ++j) acc[j] += w * b2f(hv[j]);
  }
  const float inv = 1.f / den;
  const int c0 = (lane & 31) * 8;
  ushort8 res;
  float ov[8];
#pragma unroll
  for (int j = 0; j < 8; ++j) {
    const float mine = acc[j] * inv;
    const float other = __shfl_xor(mine, 32);  // partner lane holds other head, same cols
    float o = (mine + other) * 0.5f + b2f(bias[c0 + j]);
    if (do_relu) o = fmaxf(o, 0.f);
    ov[j] = o;
    res[j] = f2b(o);
  }
  if (lane < 32) {
    *(ushort8*)&out[(size_t)n * 256 + c0] = res;
    if (out2) {
      if (*flagp) {
        float4* p = (float4*)((float*)out2 + (size_t)n * 256 + c0);
        p[0] = (float4){ov[0], ov[1], ov[2], ov[3]};
        p[1] = (float4){ov[4], ov[5], ov[6], ov[7]};
      } else {
        *(ushort8*)((unsigned short*)out2 + (size_t)n * 256 + c0) = res;
      }
    }
  }
}

// ---------------- temporal attention, grid-parallel ----------------
// logits: half-wave (32 lanes) per node, 8 nodes/block
__global__ __launch_bounds__(256) void logits_k(const unsigned short* __restrict__ emb,
                                                const unsigned short* __restrict__ params,
                                                float* __restrict__ lg) {
  const int tid = threadIdx.x;
  const int half = tid >> 5, tc = tid & 31;
  const int n = blockIdx.x * 8 + half;
  const ushort8 ev = *(const ushort8*)&emb[(size_t)n * 256 + tc * 8];
  const ushort8 wv = *(const ushort8*)&params[P_WATT + tc * 8];
  float d = 0.f;
#pragma unroll
  for (int j = 0; j < 8; ++j) d += b2f(ev[j]) * b2f(wv[j]);
#pragma unroll
  for (int off = 1; off < 32; off <<= 1) d += __shfl_xor(d, off);
  if (tc == 0) lg[n] = d + b2f(params[P_BATT]);
}

// per-audio softmax stats: 64 blocks
__global__ __launch_bounds__(256) void stats_k(const float* __restrict__ lg,
                                               float* __restrict__ mxv, float* __restrict__ invv) {
  __shared__ float red[256];
  const int a = blockIdx.x, t = threadIdx.x;
  float m = -1e30f;
  for (int i = t; i < 800; i += 256) m = fmaxf(m, lg[a * 800 + i]);
  red[t] = m; __syncthreads();
  for (int s = 128; s >= 1; s >>= 1) { if (t < s) red[t] = fmaxf(red[t], red[t + s]); __syncthreads(); }
  const float mx = red[0];
  __syncthreads();
  float sum = 0.f;
  for (int i = t; i < 800; i += 256) sum += __expf(lg[a * 800 + i] - mx);
  red[t] = sum; __syncthreads();
  for (int s = 128; s >= 1; s >>= 1) { if (t < s) red[t] += red[t + s]; __syncthreads(); }
  if (t == 0) { mxv[a] = mx; invv[a] = 1.f / red[0]; }
}

// attended: 8 blocks per audio, 100 nodes each; thread t owns column t
__global__ __launch_bounds__(256) void attended_k(const unsigned short* __restrict__ emb,
                                                  const float* __restrict__ lg,
                                                  const float* __restrict__ mxv,
                                                  const float* __restrict__ invv,
                                                  float* __restrict__ attended) {
  const int b = blockIdx.x;
  const int a = b >> 3, chunk = b & 7;
  const int t = threadIdx.x;
  __shared__ float ws[100];
  const int i0 = chunk * 100;
  const float mx = mxv[a], inv = invv[a];
  if (t < 100) ws[t] = __expf(lg[a * 800 + i0 + t] - mx) * inv;
  __syncthreads();
  float acc = 0.f;
  const unsigned short* base = emb + ((size_t)(a * 800 + i0)) * 256 + t;
#pragma unroll 4
  for (int j = 0; j < 100; ++j) acc += ws[j] * b2f(base[(size_t)j * 256]);
  atomicAdd(&attended[a * 256 + t], acc);
}

// classifier: 64 blocks; writes d_out audio part in detected dtype
__global__ __launch_bounds__(256) void cls_k(const float* __restrict__ attended,
                                             const unsigned short* __restrict__ params,
                                             void* __restrict__ out, const int* __restrict__ flag) {
  __shared__ float red[256];
  const int a = blockIdx.x, t = threadIdx.x;
  const float v = attended[a * 256 + t];
  const float p0 = v * b2f(params[P_WCLS + t * 2]);
  const float p1 = v * b2f(params[P_WCLS + t * 2 + 1]);
  red[t] = p0; __syncthreads();
  for (int s = 128; s >= 1; s >>= 1) { if (t < s) red[t] += red[t + s]; __syncthreads(); }
  const float r0 = red[0];
  __syncthreads();
  red[t] = p1; __syncthreads();
  for (int s = 128; s >= 1; s >>= 1) { if (t < s) red[t] += red[t + s]; __syncthreads(); }
  const float r1 = red[0];
  if (t == 0) {
    const float o0 = r0 + b2f(params[P_BCLS]);
    const float o1 = r1 + b2f(params[P_BCLS + 1]);
    if (*flag) {
      ((float*)out)[(size_t)NN * 256 + a * 2]     = o0;
      ((float*)out)[(size_t)NN * 256 + a * 2 + 1] = o1;
    } else {
      ((unsigned short*)out)[(size_t)NN * 256 + a * 2]     = f2b(o0);
      ((unsigned short*)out)[(size_t)NN * 256 + a * 2 + 1] = f2b(o1);
    }
  }
}

extern "C" void kernel_launch(void* const* d_in, const int* in_sizes, int n_in,
                              void* d_out, int out_size, void* d_ws, size_t ws_size,
                              hipStream_t stream) {
  (void)in_sizes; (void)n_in; (void)out_size; (void)ws_size;
  const void* x_raw  = d_in[0];
  const int*  eidx   = (const int*)d_in[1];
  // d_in[2] = batch (unused: audio = n / 800)
  const int* src = eidx;
  const int* dst = eidx + EE;

  char* ws = (char*)d_ws;
  size_t off = 0;
  auto alloc = [&](size_t bytes) -> void* {
    void* p = ws + off;
    off += (bytes + 255) & ~(size_t)255;
    return p;
  };
  int* flag              = (int*)alloc(256);
  unsigned short* params = (unsigned short*)alloc(4096 * 2);
  unsigned short* W1T    = (unsigned short*)alloc((size_t)512 * 512 * 2);
  unsigned short* W2T    = (unsigned short*)alloc((size_t)512 * 256 * 2);
  unsigned short* x16    = (unsigned short*)alloc((size_t)NN * 512 * 2);  // also hosts hrel + emb16
  unsigned short* hbig   = (unsigned short*)alloc((size_t)NN * 512 * 2);
  float* al_s   = (float*)alloc((size_t)NN * 2 * 4);
  float* al_d   = (float*)alloc((size_t)NN * 2 * 4);
  int*   counts = (int*)alloc((size_t)NN * 4);
  int*   rowp   = (int*)alloc((size_t)NN * 4);
  int*   cursor = (int*)alloc((size_t)NN * 4);
  int*   ssrc   = (int*)alloc((size_t)EE * 4);
  float* lg     = (float*)alloc((size_t)NN * 4);
  float* mxv    = (float*)alloc(NUM_AUDIOS * 4);
  float* invv   = (float*)alloc(NUM_AUDIOS * 4);
  float* attended = (float*)alloc((size_t)NUM_AUDIOS * 256 * 4);
  // Aliases into x16's region (x16 is dead after gemm1):
  unsigned short* hrel  = x16;                         // layer-1 relu output [NN,256]
  unsigned short* emb16 = x16 + (size_t)NN * 256;      // node_emb [NN,256] (bf16 copy)

  detect_k<<<dim3(1), 256, 0, stream>>>((const unsigned short*)x_raw, flag);

  hipMemsetAsync(counts, 0, (size_t)NN * 4, stream);
  hipMemsetAsync(cursor, 0, (size_t)NN * 4, stream);
  hipMemsetAsync(attended, 0, (size_t)NUM_AUDIOS * 256 * 4, stream);

  conv_x_k<<<dim3(NN * 512 / 4 / 256), 256, 0, stream>>>(x_raw, x16, flag);
  conv_params_k<<<dim3(10), 256, 0, stream>>>(d_in[4], d_in[5], d_in[6], d_in[8], d_in[9],
                                              d_in[10], d_in[11], d_in[12], d_in[13], d_in[14],
                                              params, flag);
  transpose_k<<<dim3(512 * 512 / 256), 256, 0, stream>>>(d_in[3], W1T, flag, 512, 512);
  transpose_k<<<dim3(512 * 256 / 256), 256, 0, stream>>>(d_in[7], W2T, flag, 256, 512);

  hist_k<<<dim3(EE / 256), 256, 0, stream>>>(dst, counts);
  rowptr_k<<<dim3(NUM_AUDIOS), 256, 0, stream>>>(counts, rowp);
  scatter_k<<<dim3(EE / 256), 256, 0, stream>>>(src, dst, rowp, cursor, ssrc);

  // Layer 1
  gemm_bt<<<dim3(4, 400), 256, 0, stream>>>(x16, W1T, hbig, 512, 512);
  al_k<<<dim3(NN / 4), 256, 0, stream>>>(hbig, params + P_AS1, params + P_AD1, al_s, al_d);
  agg_k<<<dim3(NN / 4), 256, 0, stream>>>(hbig, al_s, al_d, rowp, counts, ssrc,
                                          params + P_B1, hrel, 1, nullptr, flag);

  // Layer 2
  gemm_bt<<<dim3(4, 400), 256, 0, stream>>>(hrel, W2T, hbig, 256, 512);
  al_k<<<dim3(NN / 4), 256, 0, stream>>>(hbig, params + P_AS2, params + P_AD2, al_s, al_d);
  agg_k<<<dim3(NN / 4), 256, 0, stream>>>(hbig, al_s, al_d, rowp, counts, ssrc,
                                          params + P_B2, emb16, 0, d_out, flag);

  // Temporal attention + classifier (grid-parallel)
  logits_k<<<dim3(NN / 8), 256, 0, stream>>>(emb16, params, lg);
  stats_k<<<dim3(NUM_AUDIOS), 256, 0, stream>>>(lg, mxv, invv);
  attended_k<<<dim3(NUM_AUDIOS * 8), 256, 0, stream>>>(emb16, lg, mxv, invv, attended);
  cls_k<<<dim3(NUM_AUDIOS), 256, 0, stream>>>(attended, params, d_out, flag);
}

// Round 5
// 492.264 us; speedup vs baseline: 1.2992x; 1.0826x over previous
//
#include <hip/hip_runtime.h>
#include <cstdint>
#include <cstddef>

// Problem constants (fixed by the reference).
#define NUM_AUDIOS 64
#define NODES_PER  800
#define NN         51200
#define EE         409600
// IN_C=512, HID=256, OUT=256, HEADS=2 -> both GAT linears output [N, 512] (2 heads x 256)

typedef __attribute__((ext_vector_type(8))) unsigned short ushort8;
typedef __attribute__((ext_vector_type(4))) unsigned short ushort4v;
typedef __attribute__((ext_vector_type(8))) __bf16 bf16x8;
typedef __attribute__((ext_vector_type(4))) float f32x4;

__device__ __forceinline__ float b2f(unsigned short h) {
  return __uint_as_float(((unsigned)h) << 16);
}
__device__ __forceinline__ unsigned short f2b(float f) {
  unsigned u = __float_as_uint(f);
  u += 0x7fffu + ((u >> 16) & 1u);  // RNE
  return (unsigned short)(u >> 16);
}
__device__ __forceinline__ float lrelu(float v) { return v > 0.f ? v : 0.2f * v; }

// Canonical bf16 parameter block offsets (u16 units)
#define P_AS1 0
#define P_AD1 512
#define P_B1  1024
#define P_AS2 1536
#define P_AD2 2048
#define P_B2  2560
#define P_WATT 3072
#define P_BATT 3328
#define P_WCLS 3336
#define P_BCLS 3848

// ---------------- dtype probe: fp32 data read as bf16 shows huge/NaN values ----
__global__ __launch_bounds__(256) void detect_k(const unsigned short* __restrict__ x,
                                                int* __restrict__ flag) {
  __shared__ int s;
  if (threadIdx.x == 0) s = 0;
  __syncthreads();
  int big = 0;
  for (int i = threadIdx.x; i < 4096; i += 256) {
    const float v = b2f(x[i]);
    if (!(__builtin_fabsf(v) <= 1e4f)) big = 1;  // catches >1e4, inf, NaN
  }
  if (big) atomicOr(&s, 1);
  __syncthreads();
  if (threadIdx.x == 0) *flag = s;  // 1 = fp32 inputs, 0 = bf16 inputs
}

// ---------------- canonicalize x to bf16 ----------------
__global__ __launch_bounds__(256) void conv_x_k(const void* __restrict__ xraw,
                                                unsigned short* __restrict__ x16,
                                                const int* __restrict__ flag) {
  const size_t i = ((size_t)blockIdx.x * 256 + threadIdx.x) * 4;
  if (*flag) {
    const float4 v = *(const float4*)((const float*)xraw + i);
    ushort4v o;
    o[0] = f2b(v.x); o[1] = f2b(v.y); o[2] = f2b(v.z); o[3] = f2b(v.w);
    *(ushort4v*)(x16 + i) = o;
  } else {
    *(ushort4v*)(x16 + i) = *(const ushort4v*)((const unsigned short*)xraw + i);
  }
}

// ---------------- canonicalize the small parameter tensors ----------------
__global__ __launch_bounds__(256) void conv_params_k(
    const void* p0, const void* p1, const void* p2, const void* p3, const void* p4,
    const void* p5, const void* p6, const void* p7, const void* p8, const void* p9,
    unsigned short* __restrict__ dst, const int* __restrict__ flag) {
  const void* srcs[10] = {p0, p1, p2, p3, p4, p5, p6, p7, p8, p9};
  const int offs[10] = {P_AS1, P_AD1, P_B1, P_AS2, P_AD2, P_B2, P_WATT, P_BATT, P_WCLS, P_BCLS};
  const int lens[10] = {512, 512, 256, 512, 512, 256, 256, 1, 512, 2};
  const int b = blockIdx.x;
  const int f = *flag;
  for (int i = threadIdx.x; i < lens[b]; i += 256) {
    dst[offs[b] + i] = f ? f2b(((const float*)srcs[b])[i])
                         : ((const unsigned short*)srcs[b])[i];
  }
}

// ---------------- fused convert + transpose: W [K, Nc] -> WT [Nc, K] bf16 -------
__global__ __launch_bounds__(256) void transpose_k(const void* __restrict__ W,
                                                   unsigned short* __restrict__ WT,
                                                   const int* __restrict__ flag,
                                                   int K, int Nc) {
  const int idx = blockIdx.x * 256 + threadIdx.x;  // grid sized exactly K*Nc/256
  const int n = idx / K, k = idx - n * K;
  WT[idx] = (*flag) ? f2b(((const float*)W)[(size_t)k * Nc + n])
                    : ((const unsigned short*)W)[(size_t)k * Nc + n];
}

// ---------------- GEMM: C[M,Nn] = A[M,K] @ B, with B given transposed BT[Nn,K] ----
// 128x128 tile, BK=32, 256 threads (4 waves as 2x2 of 64x64), mfma 16x16x32 bf16.
// m97-style async global->LDS staging (width=16), now de-risked (NaN was input dtype).
__global__ __launch_bounds__(256) void gemm_bt(const unsigned short* __restrict__ A,
                                               const unsigned short* __restrict__ BT,
                                               unsigned short* __restrict__ C,
                                               int K, int Nn) {
  __shared__ unsigned short As[128 * 32];
  __shared__ unsigned short Bs[128 * 32];
  const int tid = threadIdx.x;
  const int wave = tid >> 6, lane = tid & 63;
  const int m0 = blockIdx.y * 128, n0 = blockIdx.x * 128;
  const int wm = wave >> 1, wn = wave & 1;
  const int row = lane & 15, quad = lane >> 4;
  f32x4 acc[4][4];
#pragma unroll
  for (int i = 0; i < 4; ++i)
#pragma unroll
    for (int j = 0; j < 4; ++j) acc[i][j] = (f32x4){0.f, 0.f, 0.f, 0.f};

  for (int k0 = 0; k0 < K; k0 += 32) {
    // LDS dest = wave-uniform base + lane*16 bytes; As layout [row][k] is linear in
    // chunk id cc (= (cc>>2)*32 + (cc&3)*8 u16 = cc*8 u16 = cc*16 bytes). ✓
#pragma unroll
    for (int r = 0; r < 2; ++r) {
      const int cc = r * 256 + wave * 64 + lane;   // chunk id 0..511
      const int arow = cc >> 2, kc = (cc & 3) * 8; // 4 chunks of 8 bf16 per row
      __builtin_amdgcn_global_load_lds(
          (const __attribute__((address_space(1))) void*)(A + (size_t)(m0 + arow) * K + k0 + kc),
          (__attribute__((address_space(3))) void*)(As + (size_t)(r * 256 + wave * 64) * 8),
          16, 0, 0);
      __builtin_amdgcn_global_load_lds(
          (const __attribute__((address_space(1))) void*)(BT + (size_t)(n0 + arow) * K + k0 + kc),
          (__attribute__((address_space(3))) void*)(Bs + (size_t)(r * 256 + wave * 64) * 8),
          16, 0, 0);
    }
    __syncthreads();  // compiler drains vmcnt before barrier

    bf16x8 af[4], bq[4];
#pragma unroll
    for (int i = 0; i < 4; ++i) {
      af[i] = *(const bf16x8*)&As[(wm * 64 + i * 16 + row) * 32 + quad * 8];
      bq[i] = *(const bf16x8*)&Bs[(wn * 64 + i * 16 + row) * 32 + quad * 8];
    }
#pragma unroll
    for (int i = 0; i < 4; ++i)
#pragma unroll
      for (int j = 0; j < 4; ++j)
        acc[i][j] = __builtin_amdgcn_mfma_f32_16x16x32_bf16(af[i], bq[j], acc[i][j], 0, 0, 0);
    __syncthreads();
  }

  // C/D layout (verified m89/m91): col = lane&15, row = quad*4 + reg
  const int col = lane & 15;
#pragma unroll
  for (int i = 0; i < 4; ++i)
#pragma unroll
    for (int j = 0; j < 4; ++j)
#pragma unroll
      for (int r = 0; r < 4; ++r) {
        const int gm = m0 + wm * 64 + i * 16 + quad * 4 + r;
        const int gn = n0 + wn * 64 + j * 16 + col;
        C[(size_t)gm * Nn + gn] = f2b(acc[i][j][r]);
      }
}

// ---------------- per-node attention logits: al_s/al_d [N,2] fp32 ----------------
__global__ __launch_bounds__(256) void al_k(const unsigned short* __restrict__ h,
                                            const unsigned short* __restrict__ a_s,
                                            const unsigned short* __restrict__ a_d,
                                            float* __restrict__ al_s, float* __restrict__ al_d) {
  const int wave = threadIdx.x >> 6, lane = threadIdx.x & 63;
  const int n = blockIdx.x * 4 + wave;
  const ushort8 hv = *(const ushort8*)&h[(size_t)n * 512 + lane * 8];
  const ushort8 sv = *(const ushort8*)&a_s[lane * 8];
  const ushort8 dv = *(const ushort8*)&a_d[lane * 8];
  float ps = 0.f, pd = 0.f;
#pragma unroll
  for (int j = 0; j < 8; ++j) {
    const float hf = b2f(hv[j]);
    ps += hf * b2f(sv[j]);
    pd += hf * b2f(dv[j]);
  }
#pragma unroll
  for (int off = 1; off < 32; off <<= 1) {  // reduce within 32-lane half (one head)
    ps += __shfl_xor(ps, off);
    pd += __shfl_xor(pd, off);
  }
  if ((lane & 31) == 0) {
    const int head = lane >> 5;
    al_s[n * 2 + head] = ps;
    al_d[n * 2 + head] = pd;
  }
}

// ---------------- CSR build ----------------
__global__ __launch_bounds__(256) void hist_k(const int* __restrict__ dst, int* __restrict__ counts) {
  const int e = blockIdx.x * 256 + threadIdx.x;
  atomicAdd(&counts[dst[e]], 1);
}

__global__ __launch_bounds__(256) void rowptr_k(const int* __restrict__ counts, int* __restrict__ row_ptr) {
  __shared__ int sh[800];
  __shared__ int pre[200];
  const int a = blockIdx.x, t = threadIdx.x;
  for (int i = t; i < 800; i += 256) sh[i] = counts[a * 800 + i];
  __syncthreads();
  if (t < 200) pre[t] = sh[t * 4] + sh[t * 4 + 1] + sh[t * 4 + 2] + sh[t * 4 + 3];
  __syncthreads();
  if (t == 0) {
    int run = 0;
    for (int i = 0; i < 200; ++i) { const int v = pre[i]; pre[i] = run; run += v; }
  }
  __syncthreads();
  if (t < 200) {
    int b = a * 6400 + pre[t];
#pragma unroll
    for (int j = 0; j < 4; ++j) { row_ptr[a * 800 + t * 4 + j] = b; b += sh[t * 4 + j]; }
  }
}

__global__ __launch_bounds__(256) void scatter_k(const int* __restrict__ src, const int* __restrict__ dst,
                                                 const int* __restrict__ row_ptr, int* __restrict__ cursor,
                                                 int* __restrict__ ssrc) {
  const int e = blockIdx.x * 256 + threadIdx.x;
  const int d = dst[e];
  const int p = atomicAdd(&cursor[d], 1);
  ssrc[row_ptr[d] + p] = src[e];
}

// ---------------- GAT aggregate: one wave per node, XCD-pinned audios ----------
// Block swizzle: audio a handled only by blocks with blockIdx%8 == a%8 (one XCD,
// assuming round-robin block->XCD dispatch) -> L2 working set ~0.8 MB << 4 MB.
__global__ __launch_bounds__(256) void agg_k(const unsigned short* __restrict__ h,
                                             const float* __restrict__ al_s, const float* __restrict__ al_d,
                                             const int* __restrict__ row_ptr, const int* __restrict__ counts,
                                             const int* __restrict__ ssrc, const unsigned short* __restrict__ bias,
                                             unsigned short* __restrict__ out, int do_relu,
                                             void* __restrict__ out2, const int* __restrict__ flagp) {
  const int wave = threadIdx.x >> 6, lane = threadIdx.x & 63;
  const int b = blockIdx.x;
  const int g = b & 7, r = b >> 3;          // g ~ XCD id, r = 0..1599
  const int a = g + 8 * (r / 200);          // audio pinned to XCD g
  const int chunk = r % 200;                // 200 blocks x 4 nodes = 800 nodes
  const int n = a * 800 + chunk * 4 + wave;
  const int head = lane >> 5;  // lanes 0-31: head0 cols, 32-63: head1 cols
  const int deg = counts[n];
  const int base = row_ptr[n];
  const float ald = al_d[n * 2 + head];
  const float self_e = lrelu(al_s[n * 2 + head] + ald);
  float mx = self_e;
  for (int i = 0; i < deg; ++i) {
    const int s = ssrc[base + i];
    mx = fmaxf(mx, lrelu(al_s[s * 2 + head] + ald));
  }
  float acc[8];
  float den;
  {
    const float w = __expf(self_e - mx);
    den = w;
    const ushort8 hv = *(const ushort8*)&h[(size_t)n * 512 + lane * 8];
#pragma unroll
    for (int j = 0; j < 8; ++j) acc[j] = w * b2f(hv[j]);
  }
  for (int i = 0; i < deg; ++i) {
    const int s = ssrc[base + i];
    const float w = __expf(lrelu(al_s[s * 2 + head] + ald) - mx);
    den += w;
    const ushort8 hv = *(const ushort8*)&h[(size_t)s * 512 + lane * 8];
#pragma unroll
    for (int j = 0; j < 8; ++j) acc[j] += w * b2f(hv[j]);
  }
  const float inv = 1.f / den;
  const int c0 = (lane & 31) * 8;
  ushort8 res;
  float ov[8];
#pragma unroll
  for (int j = 0; j < 8; ++j) {
    const float mine = acc[j] * inv;
    const float other = __shfl_xor(mine, 32);  // partner lane holds other head, same cols
    float o = (mine + other) * 0.5f + b2f(bias[c0 + j]);
    if (do_relu) o = fmaxf(o, 0.f);
    ov[j] = o;
    res[j] = f2b(o);
  }
  if (lane < 32) {
    *(ushort8*)&out[(size_t)n * 256 + c0] = res;
    if (out2) {
      if (*flagp) {
        float4* p = (float4*)((float*)out2 + (size_t)n * 256 + c0);
        p[0] = (float4){ov[0], ov[1], ov[2], ov[3]};
        p[1] = (float4){ov[4], ov[5], ov[6], ov[7]};
      } else {
        *(ushort8*)((unsigned short*)out2 + (size_t)n * 256 + c0) = res;
      }
    }
  }
}

// ---------------- temporal attention, grid-parallel ----------------
// logits: half-wave (32 lanes) per node, 8 nodes/block
__global__ __launch_bounds__(256) void logits_k(const unsigned short* __restrict__ emb,
                                                const unsigned short* __restrict__ params,
                                                float* __restrict__ lg) {
  const int tid = threadIdx.x;
  const int half = tid >> 5, tc = tid & 31;
  const int n = blockIdx.x * 8 + half;
  const ushort8 ev = *(const ushort8*)&emb[(size_t)n * 256 + tc * 8];
  const ushort8 wv = *(const ushort8*)&params[P_WATT + tc * 8];
  float d = 0.f;
#pragma unroll
  for (int j = 0; j < 8; ++j) d += b2f(ev[j]) * b2f(wv[j]);
#pragma unroll
  for (int off = 1; off < 32; off <<= 1) d += __shfl_xor(d, off);
  if (tc == 0) lg[n] = d + b2f(params[P_BATT]);
}

// per-audio softmax stats: 64 blocks
__global__ __launch_bounds__(256) void stats_k(const float* __restrict__ lg,
                                               float* __restrict__ mxv, float* __restrict__ invv) {
  __shared__ float red[256];
  const int a = blockIdx.x, t = threadIdx.x;
  float m = -1e30f;
  for (int i = t; i < 800; i += 256) m = fmaxf(m, lg[a * 800 + i]);
  red[t] = m; __syncthreads();
  for (int s = 128; s >= 1; s >>= 1) { if (t < s) red[t] = fmaxf(red[t], red[t + s]); __syncthreads(); }
  const float mx = red[0];
  __syncthreads();
  float sum = 0.f;
  for (int i = t; i < 800; i += 256) sum += __expf(lg[a * 800 + i] - mx);
  red[t] = sum; __syncthreads();
  for (int s = 128; s >= 1; s >>= 1) { if (t < s) red[t] += red[t + s]; __syncthreads(); }
  if (t == 0) { mxv[a] = mx; invv[a] = 1.f / red[0]; }
}

// attended: 8 blocks per audio, 100 nodes each; thread t owns column t
__global__ __launch_bounds__(256) void attended_k(const unsigned short* __restrict__ emb,
                                                  const float* __restrict__ lg,
                                                  const float* __restrict__ mxv,
                                                  const float* __restrict__ invv,
                                                  float* __restrict__ attended) {
  const int b = blockIdx.x;
  const int a = b >> 3, chunk = b & 7;
  const int t = threadIdx.x;
  __shared__ float ws[100];
  const int i0 = chunk * 100;
  const float mx = mxv[a], inv = invv[a];
  if (t < 100) ws[t] = __expf(lg[a * 800 + i0 + t] - mx) * inv;
  __syncthreads();
  float acc = 0.f;
  const unsigned short* base = emb + ((size_t)(a * 800 + i0)) * 256 + t;
#pragma unroll 4
  for (int j = 0; j < 100; ++j) acc += ws[j] * b2f(base[(size_t)j * 256]);
  atomicAdd(&attended[a * 256 + t], acc);
}

// classifier: 64 blocks; writes d_out audio part in detected dtype
__global__ __launch_bounds__(256) void cls_k(const float* __restrict__ attended,
                                             const unsigned short* __restrict__ params,
                                             void* __restrict__ out, const int* __restrict__ flag) {
  __shared__ float red[256];
  const int a = blockIdx.x, t = threadIdx.x;
  const float v = attended[a * 256 + t];
  const float p0 = v * b2f(params[P_WCLS + t * 2]);
  const float p1 = v * b2f(params[P_WCLS + t * 2 + 1]);
  red[t] = p0; __syncthreads();
  for (int s = 128; s >= 1; s >>= 1) { if (t < s) red[t] += red[t + s]; __syncthreads(); }
  const float r0 = red[0];
  __syncthreads();
  red[t] = p1; __syncthreads();
  for (int s = 128; s >= 1; s >>= 1) { if (t < s) red[t] += red[t + s]; __syncthreads(); }
  const float r1 = red[0];
  if (t == 0) {
    const float o0 = r0 + b2f(params[P_BCLS]);
    const float o1 = r1 + b2f(params[P_BCLS + 1]);
    if (*flag) {
      ((float*)out)[(size_t)NN * 256 + a * 2]     = o0;
      ((float*)out)[(size_t)NN * 256 + a * 2 + 1] = o1;
    } else {
      ((unsigned short*)out)[(size_t)NN * 256 + a * 2]     = f2b(o0);
      ((unsigned short*)out)[(size_t)NN * 256 + a * 2 + 1] = f2b(o1);
    }
  }
}

extern "C" void kernel_launch(void* const* d_in, const int* in_sizes, int n_in,
                              void* d_out, int out_size, void* d_ws, size_t ws_size,
                              hipStream_t stream) {
  (void)in_sizes; (void)n_in; (void)out_size; (void)ws_size;
  const void* x_raw  = d_in[0];
  const int*  eidx   = (const int*)d_in[1];
  // d_in[2] = batch (unused: audio = n / 800)
  const int* src = eidx;
  const int* dst = eidx + EE;

  char* ws = (char*)d_ws;
  size_t off = 0;
  auto alloc = [&](size_t bytes) -> void* {
    void* p = ws + off;
    off += (bytes + 255) & ~(size_t)255;
    return p;
  };
  int* flag              = (int*)alloc(256);
  unsigned short* params = (unsigned short*)alloc(4096 * 2);
  unsigned short* W1T    = (unsigned short*)alloc((size_t)512 * 512 * 2);
  unsigned short* W2T    = (unsigned short*)alloc((size_t)512 * 256 * 2);
  unsigned short* x16    = (unsigned short*)alloc((size_t)NN * 512 * 2);  // also hosts hrel + emb16
  unsigned short* hbig   = (unsigned short*)alloc((size_t)NN * 512 * 2);
  float* al_s   = (float*)alloc((size_t)NN * 2 * 4);
  float* al_d   = (float*)alloc((size_t)NN * 2 * 4);
  int*   counts = (int*)alloc((size_t)NN * 4);
  int*   rowp   = (int*)alloc((size_t)NN * 4);
  int*   cursor = (int*)alloc((size_t)NN * 4);
  int*   ssrc   = (int*)alloc((size_t)EE * 4);
  float* lg     = (float*)alloc((size_t)NN * 4);
  float* mxv    = (float*)alloc(NUM_AUDIOS * 4);
  float* invv   = (float*)alloc(NUM_AUDIOS * 4);
  float* attended = (float*)alloc((size_t)NUM_AUDIOS * 256 * 4);
  // Aliases into x16's region (x16 is dead after gemm1):
  unsigned short* hrel  = x16;                         // layer-1 relu output [NN,256]
  unsigned short* emb16 = x16 + (size_t)NN * 256;      // node_emb [NN,256] (bf16 copy)

  detect_k<<<dim3(1), 256, 0, stream>>>((const unsigned short*)x_raw, flag);

  hipMemsetAsync(counts, 0, (size_t)NN * 4, stream);
  hipMemsetAsync(cursor, 0, (size_t)NN * 4, stream);
  hipMemsetAsync(attended, 0, (size_t)NUM_AUDIOS * 256 * 4, stream);

  conv_x_k<<<dim3(NN * 512 / 4 / 256), 256, 0, stream>>>(x_raw, x16, flag);
  conv_params_k<<<dim3(10), 256, 0, stream>>>(d_in[4], d_in[5], d_in[6], d_in[8], d_in[9],
                                              d_in[10], d_in[11], d_in[12], d_in[13], d_in[14],
                                              params, flag);
  transpose_k<<<dim3(512 * 512 / 256), 256, 0, stream>>>(d_in[3], W1T, flag, 512, 512);
  transpose_k<<<dim3(512 * 256 / 256), 256, 0, stream>>>(d_in[7], W2T, flag, 256, 512);

  hist_k<<<dim3(EE / 256), 256, 0, stream>>>(dst, counts);
  rowptr_k<<<dim3(NUM_AUDIOS), 256, 0, stream>>>(counts, rowp);
  scatter_k<<<dim3(EE / 256), 256, 0, stream>>>(src, dst, rowp, cursor, ssrc);

  // Layer 1
  gemm_bt<<<dim3(4, 400), 256, 0, stream>>>(x16, W1T, hbig, 512, 512);
  al_k<<<dim3(NN / 4), 256, 0, stream>>>(hbig, params + P_AS1, params + P_AD1, al_s, al_d);
  agg_k<<<dim3(NN / 4), 256, 0, stream>>>(hbig, al_s, al_d, rowp, counts, ssrc,
                                          params + P_B1, hrel, 1, nullptr, flag);

  // Layer 2
  gemm_bt<<<dim3(4, 400), 256, 0, stream>>>(hrel, W2T, hbig, 256, 512);
  al_k<<<dim3(NN / 4), 256, 0, stream>>>(hbig, params + P_AS2, params + P_AD2, al_s, al_d);
  agg_k<<<dim3(NN / 4), 256, 0, stream>>>(hbig, al_s, al_d, rowp, counts, ssrc,
                                          params + P_B2, emb16, 0, d_out, flag);

  // Temporal attention + classifier (grid-parallel)
  logits_k<<<dim3(NN / 8), 256, 0, stream>>>(emb16, params, lg);
  stats_k<<<dim3(NUM_AUDIOS), 256, 0, stream>>>(lg, mxv, invv);
  attended_k<<<dim3(NUM_AUDIOS * 8), 256, 0, stream>>>(emb16, lg, mxv, invv, attended);
  cls_k<<<dim3(NUM_AUDIOS), 256, 0, stream>>>(attended, params, d_out, flag);
}

// Round 6
// 448.002 us; speedup vs baseline: 1.4275x; 1.0988x over previous
//
#include <hip/hip_runtime.h>
#include <cstdint>
#include <cstddef>

// Problem constants (fixed by the reference).
#define NUM_AUDIOS 64
#define NODES_PER  800
#define NN         51200
#define EE         409600
// IN_C=512, HID=256, OUT=256, HEADS=2 -> both GAT linears output [N, 512] (2 heads x 256)

typedef __attribute__((ext_vector_type(8))) unsigned short ushort8;
typedef __attribute__((ext_vector_type(4))) unsigned short ushort4v;
typedef __attribute__((ext_vector_type(8))) __bf16 bf16x8;
typedef __attribute__((ext_vector_type(4))) float f32x4;

__device__ __forceinline__ float b2f(unsigned short h) {
  return __uint_as_float(((unsigned)h) << 16);
}
__device__ __forceinline__ unsigned short f2b(float f) {
  unsigned u = __float_as_uint(f);
  u += 0x7fffu + ((u >> 16) & 1u);  // RNE
  return (unsigned short)(u >> 16);
}
__device__ __forceinline__ float lrelu(float v) { return v > 0.f ? v : 0.2f * v; }

// Canonical bf16 parameter block offsets (u16 units)
#define P_AS1 0
#define P_AD1 512
#define P_B1  1024
#define P_AS2 1536
#define P_AD2 2048
#define P_B2  2560
#define P_WATT 3072
#define P_BATT 3328
#define P_WCLS 3336
#define P_BCLS 3848

// ---------------- dtype probe: fp32 data read as bf16 shows huge/NaN values ----
__global__ __launch_bounds__(256) void detect_k(const unsigned short* __restrict__ x,
                                                int* __restrict__ flag) {
  __shared__ int s;
  if (threadIdx.x == 0) s = 0;
  __syncthreads();
  int big = 0;
  for (int i = threadIdx.x; i < 4096; i += 256) {
    const float v = b2f(x[i]);
    if (!(__builtin_fabsf(v) <= 1e4f)) big = 1;  // catches >1e4, inf, NaN
  }
  if (big) atomicOr(&s, 1);
  __syncthreads();
  if (threadIdx.x == 0) *flag = s;  // 1 = fp32 inputs, 0 = bf16 inputs
}

// ---------------- canonicalize x to bf16 ----------------
__global__ __launch_bounds__(256) void conv_x_k(const void* __restrict__ xraw,
                                                unsigned short* __restrict__ x16,
                                                const int* __restrict__ flag) {
  const size_t i = ((size_t)blockIdx.x * 256 + threadIdx.x) * 4;
  if (*flag) {
    const float4 v = *(const float4*)((const float*)xraw + i);
    ushort4v o;
    o[0] = f2b(v.x); o[1] = f2b(v.y); o[2] = f2b(v.z); o[3] = f2b(v.w);
    *(ushort4v*)(x16 + i) = o;
  } else {
    *(ushort4v*)(x16 + i) = *(const ushort4v*)((const unsigned short*)xraw + i);
  }
}

// ---------------- canonicalize the small parameter tensors ----------------
__global__ __launch_bounds__(256) void conv_params_k(
    const void* p0, const void* p1, const void* p2, const void* p3, const void* p4,
    const void* p5, const void* p6, const void* p7, const void* p8, const void* p9,
    unsigned short* __restrict__ dst, const int* __restrict__ flag) {
  const void* srcs[10] = {p0, p1, p2, p3, p4, p5, p6, p7, p8, p9};
  const int offs[10] = {P_AS1, P_AD1, P_B1, P_AS2, P_AD2, P_B2, P_WATT, P_BATT, P_WCLS, P_BCLS};
  const int lens[10] = {512, 512, 256, 512, 512, 256, 256, 1, 512, 2};
  const int b = blockIdx.x;
  const int f = *flag;
  for (int i = threadIdx.x; i < lens[b]; i += 256) {
    dst[offs[b] + i] = f ? f2b(((const float*)srcs[b])[i])
                         : ((const unsigned short*)srcs[b])[i];
  }
}

// ---------------- fused convert + transpose: W [K, Nc] -> WT [Nc, K] bf16 -------
__global__ __launch_bounds__(256) void transpose_k(const void* __restrict__ W,
                                                   unsigned short* __restrict__ WT,
                                                   const int* __restrict__ flag,
                                                   int K, int Nc) {
  const int idx = blockIdx.x * 256 + threadIdx.x;  // grid sized exactly K*Nc/256
  const int n = idx / K, k = idx - n * K;
  WT[idx] = (*flag) ? f2b(((const float*)W)[(size_t)k * Nc + n])
                    : ((const unsigned short*)W)[(size_t)k * Nc + n];
}

// ---------------- GEMM: C[M,Nn] = A[M,K] @ B, with B given transposed BT[Nn,K] ----
// 128x128 tile, BK=32, 256 threads (4 waves as 2x2 of 64x64), mfma 16x16x32 bf16.
__global__ __launch_bounds__(256) void gemm_bt(const unsigned short* __restrict__ A,
                                               const unsigned short* __restrict__ BT,
                                               unsigned short* __restrict__ C,
                                               int K, int Nn) {
  __shared__ unsigned short As[128 * 32];
  __shared__ unsigned short Bs[128 * 32];
  const int tid = threadIdx.x;
  const int wave = tid >> 6, lane = tid & 63;
  const int m0 = blockIdx.y * 128, n0 = blockIdx.x * 128;
  const int wm = wave >> 1, wn = wave & 1;
  const int row = lane & 15, quad = lane >> 4;
  f32x4 acc[4][4];
#pragma unroll
  for (int i = 0; i < 4; ++i)
#pragma unroll
    for (int j = 0; j < 4; ++j) acc[i][j] = (f32x4){0.f, 0.f, 0.f, 0.f};

  for (int k0 = 0; k0 < K; k0 += 32) {
#pragma unroll
    for (int r = 0; r < 2; ++r) {
      const int cc = r * 256 + wave * 64 + lane;   // chunk id 0..511
      const int arow = cc >> 2, kc = (cc & 3) * 8; // 4 chunks of 8 bf16 per row
      __builtin_amdgcn_global_load_lds(
          (const __attribute__((address_space(1))) void*)(A + (size_t)(m0 + arow) * K + k0 + kc),
          (__attribute__((address_space(3))) void*)(As + (size_t)(r * 256 + wave * 64) * 8),
          16, 0, 0);
      __builtin_amdgcn_global_load_lds(
          (const __attribute__((address_space(1))) void*)(BT + (size_t)(n0 + arow) * K + k0 + kc),
          (__attribute__((address_space(3))) void*)(Bs + (size_t)(r * 256 + wave * 64) * 8),
          16, 0, 0);
    }
    __syncthreads();  // compiler drains vmcnt before barrier

    bf16x8 af[4], bq[4];
#pragma unroll
    for (int i = 0; i < 4; ++i) {
      af[i] = *(const bf16x8*)&As[(wm * 64 + i * 16 + row) * 32 + quad * 8];
      bq[i] = *(const bf16x8*)&Bs[(wn * 64 + i * 16 + row) * 32 + quad * 8];
    }
#pragma unroll
    for (int i = 0; i < 4; ++i)
#pragma unroll
      for (int j = 0; j < 4; ++j)
        acc[i][j] = __builtin_amdgcn_mfma_f32_16x16x32_bf16(af[i], bq[j], acc[i][j], 0, 0, 0);
    __syncthreads();
  }

  // C/D layout (verified m89/m91): col = lane&15, row = quad*4 + reg
  const int col = lane & 15;
#pragma unroll
  for (int i = 0; i < 4; ++i)
#pragma unroll
    for (int j = 0; j < 4; ++j)
#pragma unroll
      for (int r = 0; r < 4; ++r) {
        const int gm = m0 + wm * 64 + i * 16 + quad * 4 + r;
        const int gn = n0 + wn * 64 + j * 16 + col;
        C[(size_t)gm * Nn + gn] = f2b(acc[i][j][r]);
      }
}

// ---------------- per-node attention logits: al_s/al_d [N,2] fp32 ----------------
__global__ __launch_bounds__(256) void al_k(const unsigned short* __restrict__ h,
                                            const unsigned short* __restrict__ a_s,
                                            const unsigned short* __restrict__ a_d,
                                            float* __restrict__ al_s, float* __restrict__ al_d) {
  const int wave = threadIdx.x >> 6, lane = threadIdx.x & 63;
  const int n = blockIdx.x * 4 + wave;
  const ushort8 hv = *(const ushort8*)&h[(size_t)n * 512 + lane * 8];
  const ushort8 sv = *(const ushort8*)&a_s[lane * 8];
  const ushort8 dv = *(const ushort8*)&a_d[lane * 8];
  float ps = 0.f, pd = 0.f;
#pragma unroll
  for (int j = 0; j < 8; ++j) {
    const float hf = b2f(hv[j]);
    ps += hf * b2f(sv[j]);
    pd += hf * b2f(dv[j]);
  }
#pragma unroll
  for (int off = 1; off < 32; off <<= 1) {  // reduce within 32-lane half (one head)
    ps += __shfl_xor(ps, off);
    pd += __shfl_xor(pd, off);
  }
  if ((lane & 31) == 0) {
    const int head = lane >> 5;
    al_s[n * 2 + head] = ps;
    al_d[n * 2 + head] = pd;
  }
}

// ---------------- CSR build ----------------
__global__ __launch_bounds__(256) void hist_k(const int* __restrict__ dst, int* __restrict__ counts) {
  const int e = blockIdx.x * 256 + threadIdx.x;
  atomicAdd(&counts[dst[e]], 1);
}

__global__ __launch_bounds__(256) void rowptr_k(const int* __restrict__ counts, int* __restrict__ row_ptr) {
  __shared__ int sh[800];
  __shared__ int pre[200];
  const int a = blockIdx.x, t = threadIdx.x;
  for (int i = t; i < 800; i += 256) sh[i] = counts[a * 800 + i];
  __syncthreads();
  if (t < 200) pre[t] = sh[t * 4] + sh[t * 4 + 1] + sh[t * 4 + 2] + sh[t * 4 + 3];
  __syncthreads();
  if (t == 0) {
    int run = 0;
    for (int i = 0; i < 200; ++i) { const int v = pre[i]; pre[i] = run; run += v; }
  }
  __syncthreads();
  if (t < 200) {
    int b = a * 6400 + pre[t];
#pragma unroll
    for (int j = 0; j < 4; ++j) { row_ptr[a * 800 + t * 4 + j] = b; b += sh[t * 4 + j]; }
  }
}

__global__ __launch_bounds__(256) void scatter_k(const int* __restrict__ src, const int* __restrict__ dst,
                                                 const int* __restrict__ row_ptr, int* __restrict__ cursor,
                                                 int* __restrict__ ssrc) {
  const int e = blockIdx.x * 256 + threadIdx.x;
  const int d = dst[e];
  const int p = atomicAdd(&cursor[d], 1);
  ssrc[row_ptr[d] + p] = src[e];
}

// ---------------- GAT aggregate: one wave per node, XCD-pinned audios ----------
// Edge-parallel scoring: edge i handled by lane (i&31) of each half; per-edge
// w,s broadcast via __shfl during the gather-accumulate. lrelu monotone =>
// max e_i = lrelu(max al_s_i + ald). Optional lg: fused temporal logits.
__global__ __launch_bounds__(256) void agg_k(const unsigned short* __restrict__ h,
                                             const float* __restrict__ al_s, const float* __restrict__ al_d,
                                             const int* __restrict__ row_ptr, const int* __restrict__ counts,
                                             const int* __restrict__ ssrc, const unsigned short* __restrict__ bias,
                                             unsigned short* __restrict__ out, int do_relu,
                                             void* __restrict__ out2, const int* __restrict__ flagp,
                                             const unsigned short* __restrict__ watt,
                                             float* __restrict__ lg) {
  const int wave = threadIdx.x >> 6, lane = threadIdx.x & 63;
  const int b = blockIdx.x;
  const int g = b & 7, r = b >> 3;          // g ~ XCD id, r = 0..1599
  const int a = g + 8 * (r / 200);          // audio pinned to XCD g
  const int chunk = r % 200;                // 200 blocks x 4 nodes = 800 nodes
  const int n = a * 800 + chunk * 4 + wave;
  const int head = lane >> 5;               // lanes 0-31: head0, 32-63: head1
  const int hl = lane & 31;                 // lane within half
  const int hsel = lane & 32;
  const int deg = counts[n];
  const int base = row_ptr[n];
  const float ald = al_d[n * 2 + head];
  const float self_e = lrelu(al_s[n * 2 + head] + ald);

  // Phase A: per-lane strided max of source al_s, shuffle-reduce within half.
  float m = -1e30f;
  for (int i = hl; i < deg; i += 32) {
    const int s = ssrc[base + i];
    m = fmaxf(m, al_s[s * 2 + head]);
  }
#pragma unroll
  for (int off = 1; off < 32; off <<= 1) m = fmaxf(m, __shfl_xor(m, off));
  const float mx = fmaxf(lrelu(m + ald), self_e);

  // Phase B: self row + edge tiles (w computed once per edge per head).
  const float w_self = __expf(self_e - mx);
  float acc[8];
  {
    const ushort8 hv = *(const ushort8*)&h[(unsigned)(n * 512 + lane * 8)];
#pragma unroll
    for (int j = 0; j < 8; ++j) acc[j] = w_self * b2f(hv[j]);
  }
  float dpart = 0.f;
  for (int t0 = 0; t0 < deg; t0 += 32) {
    const int cnt = min(32, deg - t0);
    int s = 0; float w = 0.f;
    if (hl < cnt) {
      s = ssrc[base + t0 + hl];
      w = __expf(lrelu(al_s[s * 2 + head] + ald) - mx);
      dpart += w;
    }
    for (int i = 0; i < cnt; ++i) {
      const float wb = __shfl(w, hsel + i);
      const int sb = __shfl(s, hsel + i);
      const ushort8 hv = *(const ushort8*)&h[(unsigned)(sb * 512 + lane * 8)];
#pragma unroll
      for (int j = 0; j < 8; ++j) acc[j] += wb * b2f(hv[j]);
    }
  }
#pragma unroll
  for (int off = 1; off < 32; off <<= 1) dpart += __shfl_xor(dpart, off);
  const float inv = 1.f / (w_self + dpart);

  const int c0 = hl * 8;
  ushort8 res;
  float ov[8];
#pragma unroll
  for (int j = 0; j < 8; ++j) {
    const float mine = acc[j] * inv;
    const float other = __shfl_xor(mine, 32);  // partner lane: other head, same cols
    float o = (mine + other) * 0.5f + b2f(bias[c0 + j]);
    if (do_relu) o = fmaxf(o, 0.f);
    ov[j] = o;
    res[j] = f2b(o);
  }
  if (lane < 32) {
    *(ushort8*)&out[(unsigned)(n * 256 + c0)] = res;
    if (out2) {
      if (*flagp) {
        float4* p = (float4*)((float*)out2 + (size_t)n * 256 + c0);
        p[0] = (float4){ov[0], ov[1], ov[2], ov[3]};
        p[1] = (float4){ov[4], ov[5], ov[6], ov[7]};
      } else {
        *(ushort8*)((unsigned short*)out2 + (size_t)n * 256 + c0) = res;
      }
    }
    if (lg) {  // fused temporal logits: dot(out_row, w_att) + b_att
      const ushort8 wv = *(const ushort8*)&watt[c0];
      float d = 0.f;
#pragma unroll
      for (int j = 0; j < 8; ++j) d += ov[j] * b2f(wv[j]);
#pragma unroll
      for (int off = 1; off < 32; off <<= 1) d += __shfl_xor(d, off);
      if (hl == 0) lg[n] = d + b2f(watt[256]);  // b_att sits right after w_att
    }
  }
}

// ---------------- temporal attention, grid-parallel ----------------
// per-audio softmax stats: 64 blocks
__global__ __launch_bounds__(256) void stats_k(const float* __restrict__ lg,
                                               float* __restrict__ mxv, float* __restrict__ invv) {
  __shared__ float red[256];
  const int a = blockIdx.x, t = threadIdx.x;
  float m = -1e30f;
  for (int i = t; i < 800; i += 256) m = fmaxf(m, lg[a * 800 + i]);
  red[t] = m; __syncthreads();
  for (int s = 128; s >= 1; s >>= 1) { if (t < s) red[t] = fmaxf(red[t], red[t + s]); __syncthreads(); }
  const float mx = red[0];
  __syncthreads();
  float sum = 0.f;
  for (int i = t; i < 800; i += 256) sum += __expf(lg[a * 800 + i] - mx);
  red[t] = sum; __syncthreads();
  for (int s = 128; s >= 1; s >>= 1) { if (t < s) red[t] += red[t + s]; __syncthreads(); }
  if (t == 0) { mxv[a] = mx; invv[a] = 1.f / red[0]; }
}

// attended: 8 blocks per audio, 100 nodes each; thread t owns column t
__global__ __launch_bounds__(256) void attended_k(const unsigned short* __restrict__ emb,
                                                  const float* __restrict__ lg,
                                                  const float* __restrict__ mxv,
                                                  const float* __restrict__ invv,
                                                  float* __restrict__ attended) {
  const int b = blockIdx.x;
  const int a = b >> 3, chunk = b & 7;
  const int t = threadIdx.x;
  __shared__ float ws[100];
  const int i0 = chunk * 100;
  const float mx = mxv[a], inv = invv[a];
  if (t < 100) ws[t] = __expf(lg[a * 800 + i0 + t] - mx) * inv;
  __syncthreads();
  float acc = 0.f;
  const unsigned short* base = emb + ((size_t)(a * 800 + i0)) * 256 + t;
#pragma unroll 4
  for (int j = 0; j < 100; ++j) acc += ws[j] * b2f(base[(size_t)j * 256]);
  atomicAdd(&attended[a * 256 + t], acc);
}

// classifier: 64 blocks; writes d_out audio part in detected dtype
__global__ __launch_bounds__(256) void cls_k(const float* __restrict__ attended,
                                             const unsigned short* __restrict__ params,
                                             void* __restrict__ out, const int* __restrict__ flag) {
  __shared__ float red[256];
  const int a = blockIdx.x, t = threadIdx.x;
  const float v = attended[a * 256 + t];
  const float p0 = v * b2f(params[P_WCLS + t * 2]);
  const float p1 = v * b2f(params[P_WCLS + t * 2 + 1]);
  red[t] = p0; __syncthreads();
  for (int s = 128; s >= 1; s >>= 1) { if (t < s) red[t] += red[t + s]; __syncthreads(); }
  const float r0 = red[0];
  __syncthreads();
  red[t] = p1; __syncthreads();
  for (int s = 128; s >= 1; s >>= 1) { if (t < s) red[t] += red[t + s]; __syncthreads(); }
  const float r1 = red[0];
  if (t == 0) {
    const float o0 = r0 + b2f(params[P_BCLS]);
    const float o1 = r1 + b2f(params[P_BCLS + 1]);
    if (*flag) {
      ((float*)out)[(size_t)NN * 256 + a * 2]     = o0;
      ((float*)out)[(size_t)NN * 256 + a * 2 + 1] = o1;
    } else {
      ((unsigned short*)out)[(size_t)NN * 256 + a * 2]     = f2b(o0);
      ((unsigned short*)out)[(size_t)NN * 256 + a * 2 + 1] = f2b(o1);
    }
  }
}

extern "C" void kernel_launch(void* const* d_in, const int* in_sizes, int n_in,
                              void* d_out, int out_size, void* d_ws, size_t ws_size,
                              hipStream_t stream) {
  (void)in_sizes; (void)n_in; (void)out_size; (void)ws_size;
  const void* x_raw  = d_in[0];
  const int*  eidx   = (const int*)d_in[1];
  // d_in[2] = batch (unused: audio = n / 800)
  const int* src = eidx;
  const int* dst = eidx + EE;

  char* ws = (char*)d_ws;
  size_t off = 0;
  auto alloc = [&](size_t bytes) -> void* {
    void* p = ws + off;
    off += (bytes + 255) & ~(size_t)255;
    return p;
  };
  int* flag              = (int*)alloc(256);
  unsigned short* params = (unsigned short*)alloc(4096 * 2);
  unsigned short* W1T    = (unsigned short*)alloc((size_t)512 * 512 * 2);
  unsigned short* W2T    = (unsigned short*)alloc((size_t)512 * 256 * 2);
  unsigned short* x16    = (unsigned short*)alloc((size_t)NN * 512 * 2);  // also hosts hrel + emb16
  unsigned short* hbig   = (unsigned short*)alloc((size_t)NN * 512 * 2);
  float* al_s   = (float*)alloc((size_t)NN * 2 * 4);
  float* al_d   = (float*)alloc((size_t)NN * 2 * 4);
  int*   counts = (int*)alloc((size_t)NN * 4);
  int*   rowp   = (int*)alloc((size_t)NN * 4);
  int*   cursor = (int*)alloc((size_t)NN * 4);
  int*   ssrc   = (int*)alloc((size_t)EE * 4);
  float* lg     = (float*)alloc((size_t)NN * 4);
  float* mxv    = (float*)alloc(NUM_AUDIOS * 4);
  float* invv   = (float*)alloc(NUM_AUDIOS * 4);
  float* attended = (float*)alloc((size_t)NUM_AUDIOS * 256 * 4);
  // Aliases into x16's region (x16 is dead after gemm1):
  unsigned short* hrel  = x16;                         // layer-1 relu output [NN,256]
  unsigned short* emb16 = x16 + (size_t)NN * 256;      // node_emb [NN,256] (bf16 copy)

  detect_k<<<dim3(1), 256, 0, stream>>>((const unsigned short*)x_raw, flag);

  hipMemsetAsync(counts, 0, (size_t)NN * 4, stream);
  hipMemsetAsync(cursor, 0, (size_t)NN * 4, stream);
  hipMemsetAsync(attended, 0, (size_t)NUM_AUDIOS * 256 * 4, stream);

  conv_x_k<<<dim3(NN * 512 / 4 / 256), 256, 0, stream>>>(x_raw, x16, flag);
  conv_params_k<<<dim3(10), 256, 0, stream>>>(d_in[4], d_in[5], d_in[6], d_in[8], d_in[9],
                                              d_in[10], d_in[11], d_in[12], d_in[13], d_in[14],
                                              params, flag);
  transpose_k<<<dim3(512 * 512 / 256), 256, 0, stream>>>(d_in[3], W1T, flag, 512, 512);
  transpose_k<<<dim3(512 * 256 / 256), 256, 0, stream>>>(d_in[7], W2T, flag, 256, 512);

  hist_k<<<dim3(EE / 256), 256, 0, stream>>>(dst, counts);
  rowptr_k<<<dim3(NUM_AUDIOS), 256, 0, stream>>>(counts, rowp);
  scatter_k<<<dim3(EE / 256), 256, 0, stream>>>(src, dst, rowp, cursor, ssrc);

  // Layer 1
  gemm_bt<<<dim3(4, 400), 256, 0, stream>>>(x16, W1T, hbig, 512, 512);
  al_k<<<dim3(NN / 4), 256, 0, stream>>>(hbig, params + P_AS1, params + P_AD1, al_s, al_d);
  agg_k<<<dim3(NN / 4), 256, 0, stream>>>(hbig, al_s, al_d, rowp, counts, ssrc,
                                          params + P_B1, hrel, 1, nullptr, flag,
                                          params + P_WATT, nullptr);

  // Layer 2
  gemm_bt<<<dim3(4, 400), 256, 0, stream>>>(hrel, W2T, hbig, 256, 512);
  al_k<<<dim3(NN / 4), 256, 0, stream>>>(hbig, params + P_AS2, params + P_AD2, al_s, al_d);
  agg_k<<<dim3(NN / 4), 256, 0, stream>>>(hbig, al_s, al_d, rowp, counts, ssrc,
                                          params + P_B2, emb16, 0, d_out, flag,
                                          params + P_WATT, lg);

  // Temporal attention + classifier (grid-parallel; logits fused into agg_k)
  stats_k<<<dim3(NUM_AUDIOS), 256, 0, stream>>>(lg, mxv, invv);
  attended_k<<<dim3(NUM_AUDIOS * 8), 256, 0, stream>>>(emb16, lg, mxv, invv, attended);
  cls_k<<<dim3(NUM_AUDIOS), 256, 0, stream>>>(attended, params, d_out, flag);
}

// Round 7
// 440.362 us; speedup vs baseline: 1.4523x; 1.0173x over previous
//
#include <hip/hip_runtime.h>
#include <cstdint>
#include <cstddef>

// Problem constants (fixed by the reference).
#define NUM_AUDIOS 64
#define NODES_PER  800
#define NN         51200
#define EE         409600
// IN_C=512, HID=256, OUT=256, HEADS=2 -> both GAT linears output [N, 512] (2 heads x 256)

typedef __attribute__((ext_vector_type(8))) unsigned short ushort8;
typedef __attribute__((ext_vector_type(4))) unsigned short ushort4v;
typedef __attribute__((ext_vector_type(8))) __bf16 bf16x8;
typedef __attribute__((ext_vector_type(4))) float f32x4;

__device__ __forceinline__ float b2f(unsigned short h) {
  return __uint_as_float(((unsigned)h) << 16);
}
__device__ __forceinline__ unsigned short f2b(float f) {
  unsigned u = __float_as_uint(f);
  u += 0x7fffu + ((u >> 16) & 1u);  // RNE
  return (unsigned short)(u >> 16);
}
__device__ __forceinline__ float lrelu(float v) { return v > 0.f ? v : 0.2f * v; }

// Canonical bf16 parameter block offsets (u16 units)
#define P_AS1 0
#define P_AD1 512
#define P_B1  1024
#define P_AS2 1536
#define P_AD2 2048
#define P_B2  2560
#define P_WATT 3072
#define P_BATT 3328
#define P_WCLS 3336
#define P_BCLS 3848

// Zero region: counts|cursor|attended|al_s1|al_d1|al_s2|al_d2 (contiguous, 2113536 B)
#define ZERO_F4 132096   // float4 count
#define ZERO_BLOCKS 516  // 516*256 = 132096

// ---------------- prolog: zero atomic buffers + dtype probe ----------------
__global__ __launch_bounds__(256) void prolog0_k(float4* __restrict__ zbase,
                                                 const unsigned short* __restrict__ x,
                                                 int* __restrict__ flag) {
  const int i = blockIdx.x * 256 + threadIdx.x;
  if (i < ZERO_F4) zbase[i] = (float4){0.f, 0.f, 0.f, 0.f};
  if (blockIdx.x == 0) {
    __shared__ int s;
    if (threadIdx.x == 0) s = 0;
    __syncthreads();
    int big = 0;
    for (int k = threadIdx.x; k < 4096; k += 256) {
      const float v = b2f(x[k]);
      if (!(__builtin_fabsf(v) <= 1e4f)) big = 1;  // catches >1e4, inf, NaN
    }
    if (big) atomicOr(&s, 1);
    __syncthreads();
    if (threadIdx.x == 0) *flag = s;  // 1 = fp32 inputs, 0 = bf16 inputs
  }
}

// ---------------- union prep: conv_x | params | transpose W1 | transpose W2 | hist
#define PB_CONV 25600
#define PB_PAR  (PB_CONV + 10)
#define PB_T1   (PB_PAR + 1024)
#define PB_T2   (PB_T1 + 512)
#define PB_HIST (PB_T2 + 1600)   // total grid = 28746

__global__ __launch_bounds__(256) void prep_k(
    const void* __restrict__ xraw, unsigned short* __restrict__ x16,
    const void* __restrict__ W1, unsigned short* __restrict__ W1T,
    const void* __restrict__ W2, unsigned short* __restrict__ W2T,
    const void* p0, const void* p1, const void* p2, const void* p3, const void* p4,
    const void* p5, const void* p6, const void* p7, const void* p8, const void* p9,
    unsigned short* __restrict__ params,
    const int* __restrict__ dst, int* __restrict__ counts,
    const int* __restrict__ flagp) {
  const int b = blockIdx.x, tid = threadIdx.x;
  const int f = *flagp;
  if (b < PB_CONV) {                       // x -> bf16
    const size_t i = ((size_t)b * 256 + tid) * 4;
    if (f) {
      const float4 v = *(const float4*)((const float*)xraw + i);
      ushort4v o;
      o[0] = f2b(v.x); o[1] = f2b(v.y); o[2] = f2b(v.z); o[3] = f2b(v.w);
      *(ushort4v*)(x16 + i) = o;
    } else {
      *(ushort4v*)(x16 + i) = *(const ushort4v*)((const unsigned short*)xraw + i);
    }
  } else if (b < PB_PAR) {                 // small params -> canonical bf16 block
    const void* srcs[10] = {p0, p1, p2, p3, p4, p5, p6, p7, p8, p9};
    const int offs[10] = {P_AS1, P_AD1, P_B1, P_AS2, P_AD2, P_B2, P_WATT, P_BATT, P_WCLS, P_BCLS};
    const int lens[10] = {512, 512, 256, 512, 512, 256, 256, 1, 512, 2};
    const int s = b - PB_CONV;
    for (int i = tid; i < lens[s]; i += 256)
      params[offs[s] + i] = f ? f2b(((const float*)srcs[s])[i])
                              : ((const unsigned short*)srcs[s])[i];
  } else if (b < PB_T1) {                  // W1 [512,512] -> W1T
    const int idx = (b - PB_PAR) * 256 + tid;
    const int n = idx >> 9, k = idx & 511;
    W1T[idx] = f ? f2b(((const float*)W1)[(size_t)k * 512 + n])
                 : ((const unsigned short*)W1)[(size_t)k * 512 + n];
  } else if (b < PB_T2) {                  // W2 [256,512] -> W2T
    const int idx = (b - PB_T1) * 256 + tid;
    const int n = idx >> 8, k = idx & 255;
    W2T[idx] = f ? f2b(((const float*)W2)[(size_t)k * 512 + n])
                 : ((const unsigned short*)W2)[(size_t)k * 512 + n];
  } else {                                 // histogram of dst
    const int e = (b - PB_T2) * 256 + tid;
    atomicAdd(&counts[dst[e]], 1);
  }
}

// ---------------- CSR build ----------------
__global__ __launch_bounds__(256) void rowptr_k(const int* __restrict__ counts, int* __restrict__ row_ptr) {
  __shared__ int sh[800];
  __shared__ int pre[200];
  const int a = blockIdx.x, t = threadIdx.x;
  for (int i = t; i < 800; i += 256) sh[i] = counts[a * 800 + i];
  __syncthreads();
  if (t < 200) pre[t] = sh[t * 4] + sh[t * 4 + 1] + sh[t * 4 + 2] + sh[t * 4 + 3];
  __syncthreads();
  if (t == 0) {
    int run = 0;
    for (int i = 0; i < 200; ++i) { const int v = pre[i]; pre[i] = run; run += v; }
  }
  __syncthreads();
  if (t < 200) {
    int b = a * 6400 + pre[t];
#pragma unroll
    for (int j = 0; j < 4; ++j) { row_ptr[a * 800 + t * 4 + j] = b; b += sh[t * 4 + j]; }
  }
}

__global__ __launch_bounds__(256) void scatter_k(const int* __restrict__ src, const int* __restrict__ dst,
                                                 const int* __restrict__ row_ptr, int* __restrict__ cursor,
                                                 int* __restrict__ ssrc) {
  const int e = blockIdx.x * 256 + threadIdx.x;
  const int d = dst[e];
  const int p = atomicAdd(&cursor[d], 1);
  ssrc[row_ptr[d] + p] = src[e];
}

// ---------------- GEMM + fused attention-logit partials ----------------
// C[M,512] = A[M,K] @ B (BT[512,K] given). 128x128 tile, mfma 16x16x32 bf16.
// Epilogue: per-row partial dots with a_s/a_d (fp32 acc), atomicAdd into al_s/al_d.
__global__ __launch_bounds__(256) void gemm_bt(const unsigned short* __restrict__ A,
                                               const unsigned short* __restrict__ BT,
                                               unsigned short* __restrict__ C,
                                               int K, int Nn,
                                               const unsigned short* __restrict__ a_s,
                                               const unsigned short* __restrict__ a_d,
                                               float* __restrict__ al_s,
                                               float* __restrict__ al_d) {
  __shared__ unsigned short As[128 * 32];
  __shared__ unsigned short Bs[128 * 32];
  const int tid = threadIdx.x;
  const int wave = tid >> 6, lane = tid & 63;
  const int m0 = blockIdx.y * 128, n0 = blockIdx.x * 128;
  const int wm = wave >> 1, wn = wave & 1;
  const int row = lane & 15, quad = lane >> 4;
  f32x4 acc[4][4];
#pragma unroll
  for (int i = 0; i < 4; ++i)
#pragma unroll
    for (int j = 0; j < 4; ++j) acc[i][j] = (f32x4){0.f, 0.f, 0.f, 0.f};

  for (int k0 = 0; k0 < K; k0 += 32) {
#pragma unroll
    for (int r = 0; r < 2; ++r) {
      const int cc = r * 256 + wave * 64 + lane;   // chunk id 0..511
      const int arow = cc >> 2, kc = (cc & 3) * 8; // 4 chunks of 8 bf16 per row
      __builtin_amdgcn_global_load_lds(
          (const __attribute__((address_space(1))) void*)(A + (size_t)(m0 + arow) * K + k0 + kc),
          (__attribute__((address_space(3))) void*)(As + (size_t)(r * 256 + wave * 64) * 8),
          16, 0, 0);
      __builtin_amdgcn_global_load_lds(
          (const __attribute__((address_space(1))) void*)(BT + (size_t)(n0 + arow) * K + k0 + kc),
          (__attribute__((address_space(3))) void*)(Bs + (size_t)(r * 256 + wave * 64) * 8),
          16, 0, 0);
    }
    __syncthreads();  // compiler drains vmcnt before barrier

    bf16x8 af[4], bq[4];
#pragma unroll
    for (int i = 0; i < 4; ++i) {
      af[i] = *(const bf16x8*)&As[(wm * 64 + i * 16 + row) * 32 + quad * 8];
      bq[i] = *(const bf16x8*)&Bs[(wn * 64 + i * 16 + row) * 32 + quad * 8];
    }
#pragma unroll
    for (int i = 0; i < 4; ++i)
#pragma unroll
      for (int j = 0; j < 4; ++j)
        acc[i][j] = __builtin_amdgcn_mfma_f32_16x16x32_bf16(af[i], bq[j], acc[i][j], 0, 0, 0);
    __syncthreads();
  }

  // C/D layout (verified m89/m91): col = lane&15, row = quad*4 + reg
  const int col = lane & 15;
#pragma unroll
  for (int i = 0; i < 4; ++i)
#pragma unroll
    for (int j = 0; j < 4; ++j)
#pragma unroll
      for (int r = 0; r < 4; ++r) {
        const int gm = m0 + wm * 64 + i * 16 + quad * 4 + r;
        const int gn = n0 + wn * 64 + j * 16 + col;
        C[(size_t)gm * Nn + gn] = f2b(acc[i][j][r]);
      }

  // Fused al partials: head = gn>>8 is wave-uniform (n0+wn*64 multiple of 64).
  {
    const int head = (n0 + wn * 64) >> 8;
    float as4[4], ad4[4];
#pragma unroll
    for (int j = 0; j < 4; ++j) {
      const int gn = n0 + wn * 64 + j * 16 + col;
      as4[j] = b2f(a_s[gn]);
      ad4[j] = b2f(a_d[gn]);
    }
#pragma unroll
    for (int i = 0; i < 4; ++i)
#pragma unroll
      for (int r = 0; r < 4; ++r) {
        float ps = 0.f, pd = 0.f;
#pragma unroll
        for (int j = 0; j < 4; ++j) { ps += acc[i][j][r] * as4[j]; pd += acc[i][j][r] * ad4[j]; }
#pragma unroll
        for (int off = 1; off < 16; off <<= 1) {  // reduce the 16 lanes sharing this row
          ps += __shfl_xor(ps, off);
          pd += __shfl_xor(pd, off);
        }
        if (col == 0) {
          const int gm = m0 + wm * 64 + i * 16 + quad * 4 + r;
          atomicAdd(&al_s[gm * 2 + head], ps);
          atomicAdd(&al_d[gm * 2 + head], pd);
        }
      }
  }
}

// ---------------- GAT aggregate: one wave per node, XCD-pinned audios ----------
// Edge-parallel scoring; per-edge w,s broadcast via __shfl. lrelu monotone =>
// max e_i = lrelu(max al_s_i + ald). Optional lg: fused temporal logits.
__global__ __launch_bounds__(256) void agg_k(const unsigned short* __restrict__ h,
                                             const float* __restrict__ al_s, const float* __restrict__ al_d,
                                             const int* __restrict__ row_ptr, const int* __restrict__ counts,
                                             const int* __restrict__ ssrc, const unsigned short* __restrict__ bias,
                                             unsigned short* __restrict__ out, int do_relu,
                                             void* __restrict__ out2, const int* __restrict__ flagp,
                                             const unsigned short* __restrict__ watt,
                                             float* __restrict__ lg) {
  const int wave = threadIdx.x >> 6, lane = threadIdx.x & 63;
  const int b = blockIdx.x;
  const int g = b & 7, r = b >> 3;          // g ~ XCD id (round-robin dispatch)
  const int a = g + 8 * (r / 200);          // audio pinned to XCD g
  const int chunk = r % 200;
  const int n = a * 800 + chunk * 4 + wave;
  const int head = lane >> 5;               // lanes 0-31: head0, 32-63: head1
  const int hl = lane & 31;
  const int hsel = lane & 32;
  const int deg = counts[n];
  const int base = row_ptr[n];
  const float ald = al_d[n * 2 + head];
  const float self_e = lrelu(al_s[n * 2 + head] + ald);

  float m = -1e30f;
  for (int i = hl; i < deg; i += 32) {
    const int s = ssrc[base + i];
    m = fmaxf(m, al_s[s * 2 + head]);
  }
#pragma unroll
  for (int off = 1; off < 32; off <<= 1) m = fmaxf(m, __shfl_xor(m, off));
  const float mx = fmaxf(lrelu(m + ald), self_e);

  const float w_self = __expf(self_e - mx);
  float acc[8];
  {
    const ushort8 hv = *(const ushort8*)&h[(unsigned)(n * 512 + lane * 8)];
#pragma unroll
    for (int j = 0; j < 8; ++j) acc[j] = w_self * b2f(hv[j]);
  }
  float dpart = 0.f;
  for (int t0 = 0; t0 < deg; t0 += 32) {
    const int cnt = min(32, deg - t0);
    int s = 0; float w = 0.f;
    if (hl < cnt) {
      s = ssrc[base + t0 + hl];
      w = __expf(lrelu(al_s[s * 2 + head] + ald) - mx);
      dpart += w;
    }
    for (int i = 0; i < cnt; ++i) {
      const float wb = __shfl(w, hsel + i);
      const int sb = __shfl(s, hsel + i);
      const ushort8 hv = *(const ushort8*)&h[(unsigned)(sb * 512 + lane * 8)];
#pragma unroll
      for (int j = 0; j < 8; ++j) acc[j] += wb * b2f(hv[j]);
    }
  }
#pragma unroll
  for (int off = 1; off < 32; off <<= 1) dpart += __shfl_xor(dpart, off);
  const float inv = 1.f / (w_self + dpart);

  const int c0 = hl * 8;
  ushort8 res;
  float ov[8];
#pragma unroll
  for (int j = 0; j < 8; ++j) {
    const float mine = acc[j] * inv;
    const float other = __shfl_xor(mine, 32);  // partner lane: other head, same cols
    float o = (mine + other) * 0.5f + b2f(bias[c0 + j]);
    if (do_relu) o = fmaxf(o, 0.f);
    ov[j] = o;
    res[j] = f2b(o);
  }
  if (lane < 32) {
    *(ushort8*)&out[(unsigned)(n * 256 + c0)] = res;
    if (out2) {
      if (*flagp) {
        float4* p = (float4*)((float*)out2 + (size_t)n * 256 + c0);
        p[0] = (float4){ov[0], ov[1], ov[2], ov[3]};
        p[1] = (float4){ov[4], ov[5], ov[6], ov[7]};
      } else {
        *(ushort8*)((unsigned short*)out2 + (size_t)n * 256 + c0) = res;
      }
    }
    if (lg) {  // fused temporal logits: dot(out_row, w_att) + b_att
      const ushort8 wv = *(const ushort8*)&watt[c0];
      float d = 0.f;
#pragma unroll
      for (int j = 0; j < 8; ++j) d += ov[j] * b2f(wv[j]);
#pragma unroll
      for (int off = 1; off < 32; off <<= 1) d += __shfl_xor(d, off);
      if (hl == 0) lg[n] = d + b2f(watt[256]);  // b_att sits right after w_att
    }
  }
}

// ---------------- temporal attention, grid-parallel ----------------
__global__ __launch_bounds__(256) void stats_k(const float* __restrict__ lg,
                                               float* __restrict__ mxv, float* __restrict__ invv) {
  __shared__ float red[256];
  const int a = blockIdx.x, t = threadIdx.x;
  float m = -1e30f;
  for (int i = t; i < 800; i += 256) m = fmaxf(m, lg[a * 800 + i]);
  red[t] = m; __syncthreads();
  for (int s = 128; s >= 1; s >>= 1) { if (t < s) red[t] = fmaxf(red[t], red[t + s]); __syncthreads(); }
  const float mx = red[0];
  __syncthreads();
  float sum = 0.f;
  for (int i = t; i < 800; i += 256) sum += __expf(lg[a * 800 + i] - mx);
  red[t] = sum; __syncthreads();
  for (int s = 128; s >= 1; s >>= 1) { if (t < s) red[t] += red[t + s]; __syncthreads(); }
  if (t == 0) { mxv[a] = mx; invv[a] = 1.f / red[0]; }
}

__global__ __launch_bounds__(256) void attended_k(const unsigned short* __restrict__ emb,
                                                  const float* __restrict__ lg,
                                                  const float* __restrict__ mxv,
                                                  const float* __restrict__ invv,
                                                  float* __restrict__ attended) {
  const int b = blockIdx.x;
  const int a = b >> 3, chunk = b & 7;
  const int t = threadIdx.x;
  __shared__ float ws[100];
  const int i0 = chunk * 100;
  const float mx = mxv[a], inv = invv[a];
  if (t < 100) ws[t] = __expf(lg[a * 800 + i0 + t] - mx) * inv;
  __syncthreads();
  float acc = 0.f;
  const unsigned short* base = emb + ((size_t)(a * 800 + i0)) * 256 + t;
#pragma unroll 4
  for (int j = 0; j < 100; ++j) acc += ws[j] * b2f(base[(size_t)j * 256]);
  atomicAdd(&attended[a * 256 + t], acc);
}

__global__ __launch_bounds__(256) void cls_k(const float* __restrict__ attended,
                                             const unsigned short* __restrict__ params,
                                             void* __restrict__ out, const int* __restrict__ flag) {
  __shared__ float red[256];
  const int a = blockIdx.x, t = threadIdx.x;
  const float v = attended[a * 256 + t];
  const float p0 = v * b2f(params[P_WCLS + t * 2]);
  const float p1 = v * b2f(params[P_WCLS + t * 2 + 1]);
  red[t] = p0; __syncthreads();
  for (int s = 128; s >= 1; s >>= 1) { if (t < s) red[t] += red[t + s]; __syncthreads(); }
  const float r0 = red[0];
  __syncthreads();
  red[t] = p1; __syncthreads();
  for (int s = 128; s >= 1; s >>= 1) { if (t < s) red[t] += red[t + s]; __syncthreads(); }
  const float r1 = red[0];
  if (t == 0) {
    const float o0 = r0 + b2f(params[P_BCLS]);
    const float o1 = r1 + b2f(params[P_BCLS + 1]);
    if (*flag) {
      ((float*)out)[(size_t)NN * 256 + a * 2]     = o0;
      ((float*)out)[(size_t)NN * 256 + a * 2 + 1] = o1;
    } else {
      ((unsigned short*)out)[(size_t)NN * 256 + a * 2]     = f2b(o0);
      ((unsigned short*)out)[(size_t)NN * 256 + a * 2 + 1] = f2b(o1);
    }
  }
}

extern "C" void kernel_launch(void* const* d_in, const int* in_sizes, int n_in,
                              void* d_out, int out_size, void* d_ws, size_t ws_size,
                              hipStream_t stream) {
  (void)in_sizes; (void)n_in; (void)out_size; (void)ws_size;
  const void* x_raw  = d_in[0];
  const int*  eidx   = (const int*)d_in[1];
  // d_in[2] = batch (unused: audio = n / 800)
  const int* src = eidx;
  const int* dst = eidx + EE;

  char* ws = (char*)d_ws;
  size_t off = 0;
  auto alloc = [&](size_t bytes) -> void* {
    void* p = ws + off;
    off += (bytes + 255) & ~(size_t)255;
    return p;
  };
  int* flag              = (int*)alloc(256);
  unsigned short* params = (unsigned short*)alloc(4096 * 2);
  unsigned short* W1T    = (unsigned short*)alloc((size_t)512 * 512 * 2);
  unsigned short* W2T    = (unsigned short*)alloc((size_t)512 * 256 * 2);
  unsigned short* x16    = (unsigned short*)alloc((size_t)NN * 512 * 2);  // also hosts hrel + emb16
  unsigned short* hbig   = (unsigned short*)alloc((size_t)NN * 512 * 2);
  // --- contiguous zero region (all sizes multiples of 256 B) ---
  int*   counts   = (int*)alloc((size_t)NN * 4);               // 204800
  int*   cursor   = (int*)alloc((size_t)NN * 4);               // 204800
  float* attended = (float*)alloc((size_t)NUM_AUDIOS * 256 * 4); // 65536
  float* al_s1    = (float*)alloc((size_t)NN * 2 * 4);         // 409600
  float* al_d1    = (float*)alloc((size_t)NN * 2 * 4);
  float* al_s2    = (float*)alloc((size_t)NN * 2 * 4);
  float* al_d2    = (float*)alloc((size_t)NN * 2 * 4);         // total 2113536 B = ZERO_F4*16
  // --- end zero region ---
  int*   rowp   = (int*)alloc((size_t)NN * 4);
  int*   ssrc   = (int*)alloc((size_t)EE * 4);
  float* lg     = (float*)alloc((size_t)NN * 4);
  float* mxv    = (float*)alloc(NUM_AUDIOS * 4);
  float* invv   = (float*)alloc(NUM_AUDIOS * 4);
  // Aliases into x16's region (x16 is dead after gemm1):
  unsigned short* hrel  = x16;                         // layer-1 relu output [NN,256]
  unsigned short* emb16 = x16 + (size_t)NN * 256;      // node_emb [NN,256] (bf16 copy)

  prolog0_k<<<dim3(ZERO_BLOCKS), 256, 0, stream>>>((float4*)counts,
                                                   (const unsigned short*)x_raw, flag);

  prep_k<<<dim3(PB_HIST), 256, 0, stream>>>(
      x_raw, x16, d_in[3], W1T, d_in[7], W2T,
      d_in[4], d_in[5], d_in[6], d_in[8], d_in[9],
      d_in[10], d_in[11], d_in[12], d_in[13], d_in[14],
      params, dst, counts, flag);

  rowptr_k<<<dim3(NUM_AUDIOS), 256, 0, stream>>>(counts, rowp);
  scatter_k<<<dim3(EE / 256), 256, 0, stream>>>(src, dst, rowp, cursor, ssrc);

  // Layer 1 (al fused into GEMM epilogue)
  gemm_bt<<<dim3(4, 400), 256, 0, stream>>>(x16, W1T, hbig, 512, 512,
                                            params + P_AS1, params + P_AD1, al_s1, al_d1);
  agg_k<<<dim3(NN / 4), 256, 0, stream>>>(hbig, al_s1, al_d1, rowp, counts, ssrc,
                                          params + P_B1, hrel, 1, nullptr, flag,
                                          params + P_WATT, nullptr);

  // Layer 2
  gemm_bt<<<dim3(4, 400), 256, 0, stream>>>(hrel, W2T, hbig, 256, 512,
                                            params + P_AS2, params + P_AD2, al_s2, al_d2);
  agg_k<<<dim3(NN / 4), 256, 0, stream>>>(hbig, al_s2, al_d2, rowp, counts, ssrc,
                                          params + P_B2, emb16, 0, d_out, flag,
                                          params + P_WATT, lg);

  // Temporal attention + classifier
  stats_k<<<dim3(NUM_AUDIOS), 256, 0, stream>>>(lg, mxv, invv);
  attended_k<<<dim3(NUM_AUDIOS * 8), 256, 0, stream>>>(emb16, lg, mxv, invv, attended);
  cls_k<<<dim3(NUM_AUDIOS), 256, 0, stream>>>(attended, params, d_out, flag);
}

// Round 8
// 438.932 us; speedup vs baseline: 1.4570x; 1.0033x over previous
//
#include <hip/hip_runtime.h>
#include <cstdint>
#include <cstddef>

// Problem constants (fixed by the reference).
#define NUM_AUDIOS 64
#define NODES_PER  800
#define NN         51200
#define EE         409600
// IN_C=512, HID=256, OUT=256, HEADS=2 -> both GAT linears output [N, 512] (2 heads x 256)

typedef __attribute__((ext_vector_type(8))) unsigned short ushort8;
typedef __attribute__((ext_vector_type(4))) unsigned short ushort4v;
typedef __attribute__((ext_vector_type(8))) __bf16 bf16x8;
typedef __attribute__((ext_vector_type(4))) float f32x4;

__device__ __forceinline__ float b2f(unsigned short h) {
  return __uint_as_float(((unsigned)h) << 16);
}
__device__ __forceinline__ unsigned short f2b(float f) {
  unsigned u = __float_as_uint(f);
  u += 0x7fffu + ((u >> 16) & 1u);  // RNE
  return (unsigned short)(u >> 16);
}
__device__ __forceinline__ float lrelu(float v) { return v > 0.f ? v : 0.2f * v; }

// Canonical bf16 parameter block offsets (u16 units)
#define P_AS1 0
#define P_AD1 512
#define P_B1  1024
#define P_AS2 1536
#define P_AD2 2048
#define P_B2  2560
#define P_WATT 3072
#define P_BATT 3328
#define P_WCLS 3336
#define P_BCLS 3848

// Zero region: counts|cursor|attended|al_s1|al_d1|al_s2|al_d2 (contiguous, 2113536 B)
#define ZERO_F4 132096   // float4 count
#define ZERO_BLOCKS 516  // 516*256 = 132096

// ---------------- prolog: zero atomic buffers + dtype probe ----------------
__global__ __launch_bounds__(256) void prolog0_k(float4* __restrict__ zbase,
                                                 const unsigned short* __restrict__ x,
                                                 int* __restrict__ flag) {
  const int i = blockIdx.x * 256 + threadIdx.x;
  if (i < ZERO_F4) zbase[i] = (float4){0.f, 0.f, 0.f, 0.f};
  if (blockIdx.x == 0) {
    __shared__ int s;
    if (threadIdx.x == 0) s = 0;
    __syncthreads();
    int big = 0;
    for (int k = threadIdx.x; k < 4096; k += 256) {
      const float v = b2f(x[k]);
      if (!(__builtin_fabsf(v) <= 1e4f)) big = 1;  // catches >1e4, inf, NaN
    }
    if (big) atomicOr(&s, 1);
    __syncthreads();
    if (threadIdx.x == 0) *flag = s;  // 1 = fp32 inputs, 0 = bf16 inputs
  }
}

// ---------------- union prep: params | transpose W1 | transpose W2 | hist ------
#define PB_PAR  10
#define PB_T1   (PB_PAR + 1024)
#define PB_T2   (PB_T1 + 512)
#define PB_HIST (PB_T2 + 1600)   // total grid = 3146

__global__ __launch_bounds__(256) void prep_k(
    const void* __restrict__ W1, unsigned short* __restrict__ W1T,
    const void* __restrict__ W2, unsigned short* __restrict__ W2T,
    const void* p0, const void* p1, const void* p2, const void* p3, const void* p4,
    const void* p5, const void* p6, const void* p7, const void* p8, const void* p9,
    unsigned short* __restrict__ params,
    const int* __restrict__ dst, int* __restrict__ counts,
    const int* __restrict__ flagp) {
  const int b = blockIdx.x, tid = threadIdx.x;
  const int f = *flagp;
  if (b < PB_PAR) {                        // small params -> canonical bf16 block
    const void* srcs[10] = {p0, p1, p2, p3, p4, p5, p6, p7, p8, p9};
    const int offs[10] = {P_AS1, P_AD1, P_B1, P_AS2, P_AD2, P_B2, P_WATT, P_BATT, P_WCLS, P_BCLS};
    const int lens[10] = {512, 512, 256, 512, 512, 256, 256, 1, 512, 2};
    const int s = b;
    for (int i = tid; i < lens[s]; i += 256)
      params[offs[s] + i] = f ? f2b(((const float*)srcs[s])[i])
                              : ((const unsigned short*)srcs[s])[i];
  } else if (b < PB_T1) {                  // W1 [512,512] -> W1T
    const int idx = (b - PB_PAR) * 256 + tid;
    const int n = idx >> 9, k = idx & 511;
    W1T[idx] = f ? f2b(((const float*)W1)[(size_t)k * 512 + n])
                 : ((const unsigned short*)W1)[(size_t)k * 512 + n];
  } else if (b < PB_T2) {                  // W2 [256,512] -> W2T
    const int idx = (b - PB_T1) * 256 + tid;
    const int n = idx >> 8, k = idx & 255;
    W2T[idx] = f ? f2b(((const float*)W2)[(size_t)k * 512 + n])
                 : ((const unsigned short*)W2)[(size_t)k * 512 + n];
  } else {                                 // histogram of dst
    const int e = (b - PB_T2) * 256 + tid;
    atomicAdd(&counts[dst[e]], 1);
  }
}

// ---------------- CSR build ----------------
__global__ __launch_bounds__(256) void rowptr_k(const int* __restrict__ counts, int* __restrict__ row_ptr) {
  __shared__ int sh[800];
  __shared__ int pre[200];
  const int a = blockIdx.x, t = threadIdx.x;
  for (int i = t; i < 800; i += 256) sh[i] = counts[a * 800 + i];
  __syncthreads();
  if (t < 200) pre[t] = sh[t * 4] + sh[t * 4 + 1] + sh[t * 4 + 2] + sh[t * 4 + 3];
  __syncthreads();
  if (t == 0) {
    int run = 0;
    for (int i = 0; i < 200; ++i) { const int v = pre[i]; pre[i] = run; run += v; }
  }
  __syncthreads();
  if (t < 200) {
    int b = a * 6400 + pre[t];
#pragma unroll
    for (int j = 0; j < 4; ++j) { row_ptr[a * 800 + t * 4 + j] = b; b += sh[t * 4 + j]; }
  }
}

__global__ __launch_bounds__(256) void scatter_k(const int* __restrict__ src, const int* __restrict__ dst,
                                                 const int* __restrict__ row_ptr, int* __restrict__ cursor,
                                                 int* __restrict__ ssrc) {
  const int e = blockIdx.x * 256 + threadIdx.x;
  const int d = dst[e];
  const int p = atomicAdd(&cursor[d], 1);
  ssrc[row_ptr[d] + p] = src[e];
}

// ---------------- GEMM core fragment+MFMA step (XOR bank-deswizzle on read) ----
__device__ __forceinline__ void mfma_tile(const unsigned short* As, const unsigned short* Bs,
                                          int wm, int wn, int row, int quad, f32x4 acc[4][4]) {
  bf16x8 af[4], bq[4];
  const int pa = (quad ^ (row & 3)) * 8;  // physical k-chunk (bank swizzle)
#pragma unroll
  for (int i = 0; i < 4; ++i) {
    af[i] = *(const bf16x8*)&As[(wm * 64 + i * 16 + row) * 32 + pa];
    bq[i] = *(const bf16x8*)&Bs[(wn * 64 + i * 16 + row) * 32 + pa];
  }
#pragma unroll
  for (int i = 0; i < 4; ++i)
#pragma unroll
    for (int j = 0; j < 4; ++j)
      acc[i][j] = __builtin_amdgcn_mfma_f32_16x16x32_bf16(af[i], bq[j], acc[i][j], 0, 0, 0);
}

// ---------------- GEMM + fused attention-logit partials ----------------
// C[M,512] = A[M,K] @ B (BT[512,K]). 128x128 tile, mfma 16x16x32 bf16.
// A dtype: bf16 (aflag null or *aflag==0, async DMA staging) or fp32
// (*aflag==1: VGPR load + convert + ds_write). XCD-swizzled 1D grid:
// g=id&7 -> XCD; row-blocks partitioned per XCD, columns innermost (A L2 reuse).
// LDS layout XOR-swizzled: logical k-chunk q of row r at physical q^(r&3).
__global__ __launch_bounds__(256) void gemm_bt(const void* __restrict__ Araw,
                                               const unsigned short* __restrict__ BT,
                                               unsigned short* __restrict__ C,
                                               int K, int Nn,
                                               const unsigned short* __restrict__ a_s,
                                               const unsigned short* __restrict__ a_d,
                                               float* __restrict__ al_s,
                                               float* __restrict__ al_d,
                                               const int* __restrict__ aflag) {
  __shared__ unsigned short As[128 * 32];
  __shared__ unsigned short Bs[128 * 32];
  const int tid = threadIdx.x;
  const int wave = tid >> 6, lane = tid & 63;
  const int bid = blockIdx.x;
  const int g = bid & 7, bt = bid >> 3;              // 8 XCDs x 200 blocks
  const int m0 = (g * 50 + (bt >> 2)) * 128;         // 50 row-blocks per XCD
  const int n0 = (bt & 3) * 128;                     // columns innermost
  const int wm = wave >> 1, wn = wave & 1;
  const int row = lane & 15, quad = lane >> 4;
  f32x4 acc[4][4];
#pragma unroll
  for (int i = 0; i < 4; ++i)
#pragma unroll
    for (int j = 0; j < 4; ++j) acc[i][j] = (f32x4){0.f, 0.f, 0.f, 0.f};

  const bool a_is_f32 = (aflag != nullptr) && (*aflag != 0);
  const unsigned short* A16 = (const unsigned short*)Araw;
  const float* A32 = (const float*)Araw;
  // staging index: chunk cc = r*256+tid; row = cc>>2; physical k-slot = cc&3;
  // global (logical) k-chunk = (cc&3) ^ (row&3)
  const int srow0 = tid >> 2;                        // r=0 row; r=1 row = +64
  const int kph = tid & 3;

  if (!a_is_f32) {
    for (int k0 = 0; k0 < K; k0 += 32) {
      __syncthreads();  // previous iteration's LDS readers done
#pragma unroll
      for (int r = 0; r < 2; ++r) {
        const int arow = r * 64 + srow0;
        const int kc = ((kph ^ (arow & 3)) * 8);
        __builtin_amdgcn_global_load_lds(
            (const __attribute__((address_space(1))) void*)(A16 + (size_t)(m0 + arow) * K + k0 + kc),
            (__attribute__((address_space(3))) void*)(As + (size_t)(r * 256 + wave * 64) * 8),
            16, 0, 0);
        __builtin_amdgcn_global_load_lds(
            (const __attribute__((address_space(1))) void*)(BT + (size_t)(n0 + arow) * K + k0 + kc),
            (__attribute__((address_space(3))) void*)(Bs + (size_t)(r * 256 + wave * 64) * 8),
            16, 0, 0);
      }
      __syncthreads();  // vmcnt(0) drain before barrier -> DMA landed
      mfma_tile(As, Bs, wm, wn, row, quad, acc);
    }
  } else {
    for (int k0 = 0; k0 < K; k0 += 32) {
      ushort8 pk[2];
#pragma unroll
      for (int r = 0; r < 2; ++r) {
        const int arow = r * 64 + srow0;
        const int kc = ((kph ^ (arow & 3)) * 8);
        const float* p = A32 + (size_t)(m0 + arow) * K + k0 + kc;
        const float4 f0 = *(const float4*)p;
        const float4 f1 = *(const float4*)(p + 4);
        pk[r][0] = f2b(f0.x); pk[r][1] = f2b(f0.y); pk[r][2] = f2b(f0.z); pk[r][3] = f2b(f0.w);
        pk[r][4] = f2b(f1.x); pk[r][5] = f2b(f1.y); pk[r][6] = f2b(f1.z); pk[r][7] = f2b(f1.w);
      }
      __syncthreads();  // previous iteration's LDS readers done
#pragma unroll
      for (int r = 0; r < 2; ++r) {
        const int arow = r * 64 + srow0;
        const int kc = ((kph ^ (arow & 3)) * 8);
        __builtin_amdgcn_global_load_lds(
            (const __attribute__((address_space(1))) void*)(BT + (size_t)(n0 + arow) * K + k0 + kc),
            (__attribute__((address_space(3))) void*)(Bs + (size_t)(r * 256 + wave * 64) * 8),
            16, 0, 0);
        *(ushort8*)&As[(size_t)(r * 256 + tid) * 8] = pk[r];
      }
      __syncthreads();  // ds_writes visible + B DMA drained (vmcnt0 before barrier)
      mfma_tile(As, Bs, wm, wn, row, quad, acc);
    }
  }

  // C/D layout (verified m89/m91): col = lane&15, row = quad*4 + reg
  const int col = lane & 15;
#pragma unroll
  for (int i = 0; i < 4; ++i)
#pragma unroll
    for (int j = 0; j < 4; ++j)
#pragma unroll
      for (int r = 0; r < 4; ++r) {
        const int gm = m0 + wm * 64 + i * 16 + quad * 4 + r;
        const int gn = n0 + wn * 64 + j * 16 + col;
        C[(size_t)gm * Nn + gn] = f2b(acc[i][j][r]);
      }

  // Fused al partials: head = gn>>8 is wave-uniform (n0+wn*64 multiple of 64).
  {
    const int head = (n0 + wn * 64) >> 8;
    float as4[4], ad4[4];
#pragma unroll
    for (int j = 0; j < 4; ++j) {
      const int gn = n0 + wn * 64 + j * 16 + col;
      as4[j] = b2f(a_s[gn]);
      ad4[j] = b2f(a_d[gn]);
    }
#pragma unroll
    for (int i = 0; i < 4; ++i)
#pragma unroll
      for (int r = 0; r < 4; ++r) {
        float ps = 0.f, pd = 0.f;
#pragma unroll
        for (int j = 0; j < 4; ++j) { ps += acc[i][j][r] * as4[j]; pd += acc[i][j][r] * ad4[j]; }
#pragma unroll
        for (int off = 1; off < 16; off <<= 1) {  // reduce the 16 lanes sharing this row
          ps += __shfl_xor(ps, off);
          pd += __shfl_xor(pd, off);
        }
        if (col == 0) {
          const int gm = m0 + wm * 64 + i * 16 + quad * 4 + r;
          atomicAdd(&al_s[gm * 2 + head], ps);
          atomicAdd(&al_d[gm * 2 + head], pd);
        }
      }
  }
}

// ---------------- GAT aggregate: one wave per node, XCD-pinned audios ----------
// Edge-parallel scoring; per-edge w,s broadcast via __shfl. lrelu monotone =>
// max e_i = lrelu(max al_s_i + ald). Optional lg: fused temporal logits.
__global__ __launch_bounds__(256) void agg_k(const unsigned short* __restrict__ h,
                                             const float* __restrict__ al_s, const float* __restrict__ al_d,
                                             const int* __restrict__ row_ptr, const int* __restrict__ counts,
                                             const int* __restrict__ ssrc, const unsigned short* __restrict__ bias,
                                             unsigned short* __restrict__ out, int do_relu,
                                             void* __restrict__ out2, const int* __restrict__ flagp,
                                             const unsigned short* __restrict__ watt,
                                             float* __restrict__ lg) {
  const int wave = threadIdx.x >> 6, lane = threadIdx.x & 63;
  const int b = blockIdx.x;
  const int g = b & 7, r = b >> 3;          // g ~ XCD id (round-robin dispatch)
  const int a = g + 8 * (r / 200);          // audio pinned to XCD g
  const int chunk = r % 200;
  const int n = a * 800 + chunk * 4 + wave;
  const int head = lane >> 5;               // lanes 0-31: head0, 32-63: head1
  const int hl = lane & 31;
  const int hsel = lane & 32;
  const int deg = counts[n];
  const int base = row_ptr[n];
  const float ald = al_d[n * 2 + head];
  const float self_e = lrelu(al_s[n * 2 + head] + ald);

  float m = -1e30f;
  for (int i = hl; i < deg; i += 32) {
    const int s = ssrc[base + i];
    m = fmaxf(m, al_s[s * 2 + head]);
  }
#pragma unroll
  for (int off = 1; off < 32; off <<= 1) m = fmaxf(m, __shfl_xor(m, off));
  const float mx = fmaxf(lrelu(m + ald), self_e);

  const float w_self = __expf(self_e - mx);
  float acc[8];
  {
    const ushort8 hv = *(const ushort8*)&h[(unsigned)(n * 512 + lane * 8)];
#pragma unroll
    for (int j = 0; j < 8; ++j) acc[j] = w_self * b2f(hv[j]);
  }
  float dpart = 0.f;
  for (int t0 = 0; t0 < deg; t0 += 32) {
    const int cnt = min(32, deg - t0);
    int s = 0; float w = 0.f;
    if (hl < cnt) {
      s = ssrc[base + t0 + hl];
      w = __expf(lrelu(al_s[s * 2 + head] + ald) - mx);
      dpart += w;
    }
    for (int i = 0; i < cnt; ++i) {
      const float wb = __shfl(w, hsel + i);
      const int sb = __shfl(s, hsel + i);
      const ushort8 hv = *(const ushort8*)&h[(unsigned)(sb * 512 + lane * 8)];
#pragma unroll
      for (int j = 0; j < 8; ++j) acc[j] += wb * b2f(hv[j]);
    }
  }
#pragma unroll
  for (int off = 1; off < 32; off <<= 1) dpart += __shfl_xor(dpart, off);
  const float inv = 1.f / (w_self + dpart);

  const int c0 = hl * 8;
  ushort8 res;
  float ov[8];
#pragma unroll
  for (int j = 0; j < 8; ++j) {
    const float mine = acc[j] * inv;
    const float other = __shfl_xor(mine, 32);  // partner lane: other head, same cols
    float o = (mine + other) * 0.5f + b2f(bias[c0 + j]);
    if (do_relu) o = fmaxf(o, 0.f);
    ov[j] = o;
    res[j] = f2b(o);
  }
  if (lane < 32) {
    *(ushort8*)&out[(unsigned)(n * 256 + c0)] = res;
    if (out2) {
      if (*flagp) {
        float4* p = (float4*)((float*)out2 + (size_t)n * 256 + c0);
        p[0] = (float4){ov[0], ov[1], ov[2], ov[3]};
        p[1] = (float4){ov[4], ov[5], ov[6], ov[7]};
      } else {
        *(ushort8*)((unsigned short*)out2 + (size_t)n * 256 + c0) = res;
      }
    }
    if (lg) {  // fused temporal logits: dot(out_row, w_att) + b_att
      const ushort8 wv = *(const ushort8*)&watt[c0];
      float d = 0.f;
#pragma unroll
      for (int j = 0; j < 8; ++j) d += ov[j] * b2f(wv[j]);
#pragma unroll
      for (int off = 1; off < 32; off <<= 1) d += __shfl_xor(d, off);
      if (hl == 0) lg[n] = d + b2f(watt[256]);  // b_att sits right after w_att
    }
  }
}

// ---------------- temporal attention, grid-parallel ----------------
__global__ __launch_bounds__(256) void stats_k(const float* __restrict__ lg,
                                               float* __restrict__ mxv, float* __restrict__ invv) {
  __shared__ float red[256];
  const int a = blockIdx.x, t = threadIdx.x;
  float m = -1e30f;
  for (int i = t; i < 800; i += 256) m = fmaxf(m, lg[a * 800 + i]);
  red[t] = m; __syncthreads();
  for (int s = 128; s >= 1; s >>= 1) { if (t < s) red[t] = fmaxf(red[t], red[t + s]); __syncthreads(); }
  const float mx = red[0];
  __syncthreads();
  float sum = 0.f;
  for (int i = t; i < 800; i += 256) sum += __expf(lg[a * 800 + i] - mx);
  red[t] = sum; __syncthreads();
  for (int s = 128; s >= 1; s >>= 1) { if (t < s) red[t] += red[t + s]; __syncthreads(); }
  if (t == 0) { mxv[a] = mx; invv[a] = 1.f / red[0]; }
}

__global__ __launch_bounds__(256) void attended_k(const unsigned short* __restrict__ emb,
                                                  const float* __restrict__ lg,
                                                  const float* __restrict__ mxv,
                                                  const float* __restrict__ invv,
                                                  float* __restrict__ attended) {
  const int b = blockIdx.x;
  const int a = b >> 3, chunk = b & 7;
  const int t = threadIdx.x;
  __shared__ float ws[100];
  const int i0 = chunk * 100;
  const float mx = mxv[a], inv = invv[a];
  if (t < 100) ws[t] = __expf(lg[a * 800 + i0 + t] - mx) * inv;
  __syncthreads();
  float acc = 0.f;
  const unsigned short* base = emb + ((size_t)(a * 800 + i0)) * 256 + t;
#pragma unroll 4
  for (int j = 0; j < 100; ++j) acc += ws[j] * b2f(base[(size_t)j * 256]);
  atomicAdd(&attended[a * 256 + t], acc);
}

__global__ __launch_bounds__(256) void cls_k(const float* __restrict__ attended,
                                             const unsigned short* __restrict__ params,
                                             void* __restrict__ out, const int* __restrict__ flag) {
  __shared__ float red[256];
  const int a = blockIdx.x, t = threadIdx.x;
  const float v = attended[a * 256 + t];
  const float p0 = v * b2f(params[P_WCLS + t * 2]);
  const float p1 = v * b2f(params[P_WCLS + t * 2 + 1]);
  red[t] = p0; __syncthreads();
  for (int s = 128; s >= 1; s >>= 1) { if (t < s) red[t] += red[t + s]; __syncthreads(); }
  const float r0 = red[0];
  __syncthreads();
  red[t] = p1; __syncthreads();
  for (int s = 128; s >= 1; s >>= 1) { if (t < s) red[t] += red[t + s]; __syncthreads(); }
  const float r1 = red[0];
  if (t == 0) {
    const float o0 = r0 + b2f(params[P_BCLS]);
    const float o1 = r1 + b2f(params[P_BCLS + 1]);
    if (*flag) {
      ((float*)out)[(size_t)NN * 256 + a * 2]     = o0;
      ((float*)out)[(size_t)NN * 256 + a * 2 + 1] = o1;
    } else {
      ((unsigned short*)out)[(size_t)NN * 256 + a * 2]     = f2b(o0);
      ((unsigned short*)out)[(size_t)NN * 256 + a * 2 + 1] = f2b(o1);
    }
  }
}

extern "C" void kernel_launch(void* const* d_in, const int* in_sizes, int n_in,
                              void* d_out, int out_size, void* d_ws, size_t ws_size,
                              hipStream_t stream) {
  (void)in_sizes; (void)n_in; (void)out_size; (void)ws_size;
  const void* x_raw  = d_in[0];
  const int*  eidx   = (const int*)d_in[1];
  // d_in[2] = batch (unused: audio = n / 800)
  const int* src = eidx;
  const int* dst = eidx + EE;

  char* ws = (char*)d_ws;
  size_t off = 0;
  auto alloc = [&](size_t bytes) -> void* {
    void* p = ws + off;
    off += (bytes + 255) & ~(size_t)255;
    return p;
  };
  int* flag              = (int*)alloc(256);
  unsigned short* params = (unsigned short*)alloc(4096 * 2);
  unsigned short* W1T    = (unsigned short*)alloc((size_t)512 * 512 * 2);
  unsigned short* W2T    = (unsigned short*)alloc((size_t)512 * 256 * 2);
  unsigned short* scr    = (unsigned short*)alloc((size_t)NN * 512 * 2);  // hrel + emb16
  unsigned short* hbig   = (unsigned short*)alloc((size_t)NN * 512 * 2);
  // --- contiguous zero region (all sizes multiples of 256 B) ---
  int*   counts   = (int*)alloc((size_t)NN * 4);               // 204800
  int*   cursor   = (int*)alloc((size_t)NN * 4);               // 204800
  float* attended = (float*)alloc((size_t)NUM_AUDIOS * 256 * 4); // 65536
  float* al_s1    = (float*)alloc((size_t)NN * 2 * 4);         // 409600
  float* al_d1    = (float*)alloc((size_t)NN * 2 * 4);
  float* al_s2    = (float*)alloc((size_t)NN * 2 * 4);
  float* al_d2    = (float*)alloc((size_t)NN * 2 * 4);         // total 2113536 B = ZERO_F4*16
  // --- end zero region ---
  int*   rowp   = (int*)alloc((size_t)NN * 4);
  int*   ssrc   = (int*)alloc((size_t)EE * 4);
  float* lg     = (float*)alloc((size_t)NN * 4);
  float* mxv    = (float*)alloc(NUM_AUDIOS * 4);
  float* invv   = (float*)alloc(NUM_AUDIOS * 4);
  unsigned short* hrel  = scr;                         // layer-1 relu output [NN,256]
  unsigned short* emb16 = scr + (size_t)NN * 256;      // node_emb [NN,256] (bf16 copy)

  prolog0_k<<<dim3(ZERO_BLOCKS), 256, 0, stream>>>((float4*)counts,
                                                   (const unsigned short*)x_raw, flag);

  prep_k<<<dim3(PB_HIST), 256, 0, stream>>>(
      d_in[3], W1T, d_in[7], W2T,
      d_in[4], d_in[5], d_in[6], d_in[8], d_in[9],
      d_in[10], d_in[11], d_in[12], d_in[13], d_in[14],
      params, dst, counts, flag);

  rowptr_k<<<dim3(NUM_AUDIOS), 256, 0, stream>>>(counts, rowp);
  scatter_k<<<dim3(EE / 256), 256, 0, stream>>>(src, dst, rowp, cursor, ssrc);

  // Layer 1 (x conversion fused into GEMM staging; al fused into epilogue)
  gemm_bt<<<dim3(1600), 256, 0, stream>>>(x_raw, W1T, hbig, 512, 512,
                                          params + P_AS1, params + P_AD1, al_s1, al_d1, flag);
  agg_k<<<dim3(NN / 4), 256, 0, stream>>>(hbig, al_s1, al_d1, rowp, counts, ssrc,
                                          params + P_B1, hrel, 1, nullptr, flag,
                                          params + P_WATT, nullptr);

  // Layer 2
  gemm_bt<<<dim3(1600), 256, 0, stream>>>(hrel, W2T, hbig, 256, 512,
                                          params + P_AS2, params + P_AD2, al_s2, al_d2, nullptr);
  agg_k<<<dim3(NN / 4), 256, 0, stream>>>(hbig, al_s2, al_d2, rowp, counts, ssrc,
                                          params + P_B2, emb16, 0, d_out, flag,
                                          params + P_WATT, lg);

  // Temporal attention + classifier
  stats_k<<<dim3(NUM_AUDIOS), 256, 0, stream>>>(lg, mxv, invv);
  attended_k<<<dim3(NUM_AUDIOS * 8), 256, 0, stream>>>(emb16, lg, mxv, invv, attended);
  cls_k<<<dim3(NUM_AUDIOS), 256, 0, stream>>>(attended, params, d_out, flag);
}